// Round 9
// baseline (211.481 us; speedup 1.0000x reference)
//
#include <hip/hip_runtime.h>
#include <hip/hip_bf16.h>

constexpr int B = 4;
constexpr int N = 1024;
constexpr int D = 1024;
constexpr int H = 16;
constexpr int DEPTH = 64;
constexpr int W = 32;
constexpr int LDQKV = 3072;   // fused q|k|v row stride (f16 elements)

typedef _Float16 f16x8 __attribute__((ext_vector_type(8)));
typedef float f32x4 __attribute__((ext_vector_type(4)));
typedef unsigned short us8 __attribute__((ext_vector_type(8)));
typedef unsigned short us4 __attribute__((ext_vector_type(4)));

__device__ __forceinline__ float h2f(unsigned short u) {
  return (float)__builtin_bit_cast(_Float16, u);
}

// ---------------------------------------------------------------------------
// async global->LDS, 16B per lane (wave-uniform LDS base, HW adds lane*16)
// ---------------------------------------------------------------------------
__device__ __forceinline__ void load_lds16(const void* g, void* l) {
  unsigned int lo = (unsigned int)(unsigned long long)l;
  __builtin_amdgcn_global_load_lds(
      (const __attribute__((address_space(1))) unsigned int*)g,
      (__attribute__((address_space(3))) unsigned int*)lo, 16, 0, 0);
}

// ---------------------------------------------------------------------------
// fp32 -> fp16 (single hi plane), 8 elems/thread
// ---------------------------------------------------------------------------
__global__ __launch_bounds__(256) void cvt_half(const float* __restrict__ x,
                                                unsigned short* __restrict__ o) {
  const size_t i = ((size_t)blockIdx.x * 256 + threadIdx.x) * 8;
  float4 a = *(const float4*)(x + i);
  float4 b = *(const float4*)(x + i + 4);
  float xs[8] = {a.x, a.y, a.z, a.w, b.x, b.y, b.z, b.w};
  us8 hv;
#pragma unroll
  for (int j = 0; j < 8; j++) {
    _Float16 h = (_Float16)xs[j];
    hv[j] = __builtin_bit_cast(unsigned short, h);
  }
  *(us8*)(o + i) = hv;
}

// ---------------------------------------------------------------------------
// weight [K=1024][N=1024] -> transposed fp16 split BT[rowOff+n][k]:
// hi = (f16)w ; lo = (f16)((w - hi) * 1024)   (scaled to stay fp16-normal)
// ---------------------------------------------------------------------------
__global__ __launch_bounds__(256) void txp_cvt_h(const float* __restrict__ w,
                                                 unsigned short* __restrict__ bth,
                                                 unsigned short* __restrict__ btl,
                                                 int rowOff) {
  __shared__ float sf[64][65];
  const int t = threadIdx.x;
  const int tn = (blockIdx.x & 15) * 64;  // src col block
  const int tk = (blockIdx.x >> 4) * 64;  // src row block
#pragma unroll
  for (int i = 0; i < 4; i++) {
    int f = i * 256 + t;
    int r = f >> 4, c4 = (f & 15) * 4;
    float4 v = *(const float4*)(w + (size_t)(tk + r) * 1024 + tn + c4);
    sf[r][c4 + 0] = v.x; sf[r][c4 + 1] = v.y;
    sf[r][c4 + 2] = v.z; sf[r][c4 + 3] = v.w;
  }
  __syncthreads();
  const int n = t >> 2;            // out row (src col)
  const int kc = (t & 3) * 16;     // k chunk
  us8 hv[2], lv[2];
#pragma unroll
  for (int half = 0; half < 2; half++) {
#pragma unroll
    for (int j = 0; j < 8; j++) {
      float x = sf[kc + half * 8 + j][n];
      _Float16 h = (_Float16)x;
      _Float16 l = (_Float16)((x - (float)h) * 1024.0f);
      hv[half][j] = __builtin_bit_cast(unsigned short, h);
      lv[half][j] = __builtin_bit_cast(unsigned short, l);
    }
  }
  size_t dst = (size_t)(rowOff + tn + n) * 1024 + tk + kc;
  *(us8*)(bth + dst) = hv[0];
  *(us8*)(bth + dst + 8) = hv[1];
  *(us8*)(btl + dst) = lv[0];
  *(us8*)(btl + dst + 8) = lv[1];
}

__global__ void bias_concat(const float* __restrict__ bq, const float* __restrict__ bk,
                            const float* __restrict__ bv, float* __restrict__ dst) {
  int i = blockIdx.x * 256 + threadIdx.x;
  dst[i] = i < 1024 ? bq[i] : (i < 2048 ? bk[i - 1024] : bv[i - 2048]);
}

// ---------------------------------------------------------------------------
// fp16 2-term split MFMA GEMM, 3-buffer counted-vmcnt pipeline (T3+T4):
//   C = Ah@Bh + (Ah*2^-10)@(Bl*2^10) + bias
// 128x128 tile, BK=32, 4 waves, 16x16x32 f16 MFMA, 4x4 frags/wave.
// LDS: 3 buffers x {A|Bh|Bl} x 8KB = 72 KB -> 2 blocks/CU. Loads run 2 tiles
// ahead; per-wave ledger: 6 loads/stage, steady-state 12 outstanding,
// vmcnt(6) waits only tile-t's loads (NEVER 0 in main loop). Raw s_barrier
// (no compiler vmcnt(0) drain) + sched_barrier(0) pins ds_reads after it.
// Granule swizzle k'=k^((r>>1)&3) on global source + ds_read. T1 XCD swizzle;
// T5 setprio around MFMA cluster.
// ---------------------------------------------------------------------------
template <bool F16OUT>
__global__ __launch_bounds__(256) void gemm_f16(
    const unsigned short* __restrict__ A16, const unsigned short* __restrict__ BTh,
    const unsigned short* __restrict__ BTl, const float* __restrict__ bias,
    void* __restrict__ Cout, int K, int Nn) {
  // buffer b at b*12288; planes: A +0, Bh +4096, Bl +8192 (elements)
  __shared__ __align__(16) unsigned short sLDS[3 * 12288];

  const int tid = threadIdx.x;
  const int lane = tid & 63;
  const int wave = tid >> 6;
  const int wr = wave >> 1, wc = wave & 1;

  // T1 XCD-aware swizzle (nwg % 8 == 0 for both launches)
  const int gx = gridDim.x;
  const int nwg = gx * gridDim.y;
  int bid = blockIdx.y * gx + blockIdx.x;
  bid = (bid & 7) * (nwg >> 3) + (bid >> 3);
  const int bm = (bid / gx) * 128;
  const int bn = (bid % gx) * 128;

  // staging: plane = 8KB = 8 chunks of (64 lanes x 16B); wave stages chunks
  // {wave, wave+4}. Pre-swizzled global source (rule #21), linear LDS dest.
  size_t aoff[2], boff[2];
  int ldsoff[2];
#pragma unroll
  for (int c = 0; c < 2; c++) {
    const int chunk = wave + 4 * c;
    const int e = chunk * 512 + lane * 8;   // linear LDS element
    const int r = e >> 5;                   // tile row
    const int kpos = (e >> 3) & 3;          // granule position in row
    const int ksrc = kpos ^ ((r >> 1) & 3); // swizzle: source granule
    aoff[c] = (size_t)(bm + r) * K + ksrc * 8;
    boff[c] = (size_t)(bn + r) * K + ksrc * 8;
    ldsoff[c] = chunk * 512;
  }

  const int fr = lane & 15;
  const int fkg = lane >> 4;

  // ds_read offsets within one plane
  int aroff[4], broff[4];
#pragma unroll
  for (int m = 0; m < 4; m++) {
    const int ra = wr * 64 + m * 16 + fr;
    aroff[m] = ra * 32 + ((fkg ^ ((ra >> 1) & 3)) << 3);
    const int rb = wc * 64 + m * 16 + fr;
    broff[m] = rb * 32 + ((fkg ^ ((rb >> 1) & 3)) << 3);
  }

  auto STAGE = [&](int buf, int k0) {
    unsigned short* base = sLDS + buf * 12288;
#pragma unroll
    for (int c = 0; c < 2; c++) {
      load_lds16(A16 + aoff[c] + k0, base + ldsoff[c]);
      load_lds16(BTh + boff[c] + k0, base + 4096 + ldsoff[c]);
      load_lds16(BTl + boff[c] + k0, base + 8192 + ldsoff[c]);
    }
  };

  f32x4 acc[4][4] = {};

  const int NT = K >> 5;
  // prologue: stage tiles 0 and 1 (12 loads outstanding per wave)
  STAGE(0, 0);
  STAGE(1, 32);

  int cur = 0;
  for (int t = 0; t < NT; t++) {
    if (t == NT - 1) {
      asm volatile("s_waitcnt vmcnt(0)" ::: "memory");
    } else {
      asm volatile("s_waitcnt vmcnt(6)" ::: "memory");  // tile t landed
    }
    __builtin_amdgcn_s_barrier();        // all waves' tile-t writes visible
    __builtin_amdgcn_sched_barrier(0);   // pin ds_reads below the barrier
    if (t + 2 < NT) {
      const int nb = (cur + 2 >= 3) ? cur - 1 : cur + 2;  // (cur+2)%3
      STAGE(nb, (t + 2) << 5);           // safe: compute(t-1) done everywhere
    }
    const int bo_ = cur * 12288;
    f16x8 a[4], as_[4], bh[4], bl[4];
#pragma unroll
    for (int m = 0; m < 4; m++) {
      a[m] = *(const f16x8*)(sLDS + bo_ + aroff[m]);
      as_[m] = a[m] * (_Float16)0.0009765625f;  // *2^-10, exact
    }
#pragma unroll
    for (int n = 0; n < 4; n++) {
      bh[n] = *(const f16x8*)(sLDS + bo_ + 4096 + broff[n]);
      bl[n] = *(const f16x8*)(sLDS + bo_ + 8192 + broff[n]);
    }
    __builtin_amdgcn_s_setprio(1);
#pragma unroll
    for (int m = 0; m < 4; m++)
#pragma unroll
      for (int n = 0; n < 4; n++) {
        acc[m][n] = __builtin_amdgcn_mfma_f32_16x16x32_f16(a[m], bh[n], acc[m][n], 0, 0, 0);
        acc[m][n] = __builtin_amdgcn_mfma_f32_16x16x32_f16(as_[m], bl[n], acc[m][n], 0, 0, 0);
      }
    __builtin_amdgcn_s_setprio(0);
    cur = (cur + 1 == 3) ? 0 : cur + 1;
  }

  // epilogue: C/D layout col=lane&15, row=(lane>>4)*4+j
#pragma unroll
  for (int m = 0; m < 4; m++) {
    const int row = bm + wr * 64 + m * 16 + fkg * 4;
#pragma unroll
    for (int n = 0; n < 4; n++) {
      const int col = bn + wc * 64 + n * 16 + fr;
      const float bsv = bias[col];
#pragma unroll
      for (int j = 0; j < 4; j++) {
        const float v = acc[m][n][j] + bsv;
        if constexpr (F16OUT) {
          ((unsigned short*)Cout)[(size_t)(row + j) * Nn + col] =
              __builtin_bit_cast(unsigned short, (_Float16)v);
        } else {
          ((float*)Cout)[(size_t)(row + j) * Nn + col] = v;
        }
      }
    }
  }
}

// ---------------------------------------------------------------------------
// Vsum two-stage over fp16 v: part[b,chunk,d] = sum of 64 rows; then combine.
// ---------------------------------------------------------------------------
__global__ __launch_bounds__(256) void vsum_part(const unsigned short* __restrict__ v,
                                                 float* __restrict__ part) {
  const int b = blockIdx.x >> 4;
  const int chunk = blockIdx.x & 15;
  const int d4 = threadIdx.x * 4;
  const unsigned short* p =
      v + (size_t)b * N * LDQKV + (size_t)chunk * 64 * LDQKV + d4;
  float4 s = {0.f, 0.f, 0.f, 0.f};
#pragma unroll 8
  for (int n = 0; n < 64; n++) {
    us4 t = *(const us4*)(p + (size_t)n * LDQKV);
    s.x += h2f(t[0]); s.y += h2f(t[1]); s.z += h2f(t[2]); s.w += h2f(t[3]);
  }
  *(float4*)(part + (size_t)blockIdx.x * 1024 + d4) = s;
}

__global__ __launch_bounds__(256) void vsum_comb(const float* __restrict__ part,
                                                 float* __restrict__ vsum) {
  const int i = blockIdx.x * 256 + threadIdx.x;  // b*1024 + d
  const int b = i >> 10, d = i & 1023;
  float s = 0.f;
#pragma unroll
  for (int c = 0; c < 16; c++) s += part[(size_t)(b * 16 + c) * 1024 + d];
  vsum[i] = s;
}

// ---------------------------------------------------------------------------
// pass1: 256-thread blocks, 4 heads (same b,n) per block — one wave per head.
// graph row loaded once per block. Gather-dot 32 keys, closed-form softmax,
// writes p/base and the fp16 O-GEMM input plane.
// ---------------------------------------------------------------------------
__global__ __launch_bounds__(256) void attn_pass1(
    const unsigned short* __restrict__ qkv16, const float* __restrict__ vsum,
    const int* __restrict__ graph, float* __restrict__ pbuf,
    float* __restrict__ basebuf, unsigned short* __restrict__ O16) {
  const int blk = blockIdx.x;         // b*4096 + hg*1024 + n
  const int n = blk & (N - 1);
  const int hg = (blk >> 10) & 3;
  const int b = blk >> 12;
  const int wave = threadIdx.x >> 6;
  const int lane = threadIdx.x & 63;
  const int h = hg * 4 + wave;
  const int bid = (b * H + h) * N + n;  // original row id

  __shared__ float q_sh[4][DEPTH];
  __shared__ int g_sh[W];
  __shared__ float p_sh[4][W];

  const unsigned short* qrow = qkv16 + (size_t)(b * N + n) * LDQKV + h * DEPTH;
  q_sh[wave][lane] = h2f(qrow[lane]);
  if (threadIdx.x < W) g_sh[threadIdx.x] = graph[n * W + threadIdx.x];
  __syncthreads();

  const int w = lane >> 1;
  const int half = lane & 1;
  const unsigned short* krow =
      qkv16 + 1024 + (size_t)(b * N + g_sh[w]) * LDQKV + h * DEPTH + half * 32;
  float acc = 0.f;
#pragma unroll
  for (int j8 = 0; j8 < 4; j8++) {
    us8 kv = *(const us8*)(krow + j8 * 8);
    const float* qh = &q_sh[wave][half * 32 + j8 * 8];
#pragma unroll
    for (int e = 0; e < 8; e++) acc += h2f(kv[e]) * qh[e];
  }
  acc += __shfl_xor(acc, 1);
  const float dot = acc * 0.125f;

  float m = dot;
#pragma unroll
  for (int off = 2; off < 64; off <<= 1) m = fmaxf(m, __shfl_xor(m, off));
  m = fmaxf(m, 0.f);

  const float e = expf(dot - m);
  float s = e;
#pragma unroll
  for (int off = 1; off < 64; off <<= 1) s += __shfl_xor(s, off);
  s *= 0.5f;

  const float em = expf(-m);
  const float Z = (float)(N - W) * em + s;
  const float inv = 1.f / Z;
  const float base = em * inv;
  const float pw = e * inv;

  if (half == 0) p_sh[wave][w] = pw;
  __syncthreads();

  if (half == 0) pbuf[(size_t)bid * W + w] = pw;
  if (lane == 0) basebuf[bid] = base;

  const unsigned short* vbase = qkv16 + 2048;
  const int col = h * DEPTH + lane;
  float ov = base * vsum[b * D + col];
#pragma unroll 4
  for (int ww = 0; ww < W; ww++) {
    ov += (p_sh[wave][ww] - base) *
          h2f(vbase[(size_t)(b * N + g_sh[ww]) * LDQKV + col]);
  }
  _Float16 hh = (_Float16)ov;
  O16[(size_t)(b * N + n) * D + col] = __builtin_bit_cast(unsigned short, hh);
}

// ---------------------------------------------------------------------------
// attn row fill: base everywhere, p_w at graph positions. NT stores.
// ---------------------------------------------------------------------------
__global__ __launch_bounds__(256) void attn_fill(
    const float* __restrict__ pbuf, const float* __restrict__ basebuf,
    const int* __restrict__ graph, float* __restrict__ attn) {
  const int bid = blockIdx.x;
  const int n = bid & (N - 1);
  __shared__ float row[N];

  const float base = basebuf[bid];
  f32x4 b4 = {base, base, base, base};
  f32x4* row4 = (f32x4*)row;
  row4[threadIdx.x] = b4;
  __syncthreads();
  if (threadIdx.x < W) {
    const int g = graph[n * W + threadIdx.x];
    row[g] = pbuf[(size_t)bid * W + threadIdx.x];
  }
  __syncthreads();
  f32x4* dst = (f32x4*)(attn + (size_t)bid * N);
  __builtin_nontemporal_store(row4[threadIdx.x], dst + threadIdx.x);
}

// ---------------------------------------------------------------------------
extern "C" void kernel_launch(void* const* d_in, const int* in_sizes, int n_in,
                              void* d_out, int out_size, void* d_ws, size_t ws_size,
                              hipStream_t stream) {
  const float* hidden = (const float*)d_in[0];
  const float* wq = (const float*)d_in[1];
  const float* bq = (const float*)d_in[2];
  const float* wk = (const float*)d_in[3];
  const float* bk = (const float*)d_in[4];
  const float* wv = (const float*)d_in[5];
  const float* bv = (const float*)d_in[6];
  const float* wo = (const float*)d_in[7];
  const float* bo = (const float*)d_in[8];
  const int* graph = (const int*)d_in[9];

  float* out0 = (float*)d_out;                 // (B,N,D) final output
  float* attnp = out0 + (size_t)B * N * D;     // (B,H,N,N) — also scratch arena

  // scratch carved from attn region (64M floats; fully rewritten by attn_fill)
  const size_t M1 = (size_t)1024 * 1024;
  unsigned short* qkv16 = (unsigned short*)attnp;              // [4096][3072] f16
  unsigned short* A16 = (unsigned short*)(attnp + 6 * M1);     // [4096][1024] f16
  unsigned short* BTh = (unsigned short*)(attnp + 8 * M1);     // [3072][1024] f16
  unsigned short* BTl = (unsigned short*)(attnp + 10 * M1);
  unsigned short* WoTh = (unsigned short*)(attnp + 12 * M1);   // [1024][1024] f16
  unsigned short* WoTl = (unsigned short*)(attnp + 13 * M1);
  unsigned short* O16 = (unsigned short*)(attnp + 14 * M1);    // [4096][1024] f16
  float* biasq = attnp + 16 * M1;                              // 3072
  float* vpart = attnp + 16 * M1 + 8192;                       // [64][1024]

  // small workspace (proven size)
  float* pbuf = (float*)d_ws;                  // B*H*N*W
  float* basebuf = pbuf + (size_t)B * H * N * W;
  float* vsumb = basebuf + (size_t)B * H * N;

  // converts
  cvt_half<<<2048, 256, 0, stream>>>(hidden, A16);
  txp_cvt_h<<<256, 256, 0, stream>>>(wq, BTh, BTl, 0);
  txp_cvt_h<<<256, 256, 0, stream>>>(wk, BTh, BTl, 1024);
  txp_cvt_h<<<256, 256, 0, stream>>>(wv, BTh, BTl, 2048);
  txp_cvt_h<<<256, 256, 0, stream>>>(wo, WoTh, WoTl, 0);
  bias_concat<<<12, 256, 0, stream>>>(bq, bk, bv, biasq);

  // fused projection: qkv16 = f16(hidden @ [Wq | Wk | Wv] + [bq | bk | bv])
  gemm_f16<true><<<dim3(24, 32), 256, 0, stream>>>(A16, BTh, BTl, biasq,
                                                   qkv16, 1024, 3072);

  vsum_part<<<64, 256, 0, stream>>>(qkv16 + 2048, vpart);
  vsum_comb<<<16, 256, 0, stream>>>(vpart, vsumb);

  attn_pass1<<<B * 4 * N, 256, 0, stream>>>(qkv16, vsumb, graph, pbuf, basebuf,
                                            O16);

  // O-projection (fp32 out)
  gemm_f16<false><<<dim3(8, 32), 256, 0, stream>>>(O16, WoTh, WoTl, bo,
                                                   out0, 1024, 1024);

  attn_fill<<<B * H * N, 256, 0, stream>>>(pbuf, basebuf, graph, attnp);
}

// Round 10
// 206.164 us; speedup vs baseline: 1.0258x; 1.0258x over previous
//
#include <hip/hip_runtime.h>
#include <hip/hip_bf16.h>

constexpr int B = 4;
constexpr int N = 1024;
constexpr int D = 1024;
constexpr int H = 16;
constexpr int DEPTH = 64;
constexpr int W = 32;
constexpr int LDQKV = 3072;   // fused q|k|v row stride (f16 elements)

typedef _Float16 f16x8 __attribute__((ext_vector_type(8)));
typedef float f32x4 __attribute__((ext_vector_type(4)));
typedef unsigned short us8 __attribute__((ext_vector_type(8)));
typedef unsigned short us4 __attribute__((ext_vector_type(4)));

__device__ __forceinline__ float h2f(unsigned short u) {
  return (float)__builtin_bit_cast(_Float16, u);
}

// ---------------------------------------------------------------------------
// async global->LDS, 16B per lane (wave-uniform LDS base, HW adds lane*16)
// ---------------------------------------------------------------------------
__device__ __forceinline__ void load_lds16(const void* g, void* l) {
  unsigned int lo = (unsigned int)(unsigned long long)l;
  __builtin_amdgcn_global_load_lds(
      (const __attribute__((address_space(1))) unsigned int*)g,
      (__attribute__((address_space(3))) unsigned int*)lo, 16, 0, 0);
}

// ---------------------------------------------------------------------------
// Fused prep: grid sections
//   [0, 2048)       cvt_half: hidden fp32 -> A16 fp16
//   [2048, 3072)    txp_cvt:  wq/wk/wv/wo -> transposed fp16 hi/lo split
//   [3072, 3084)    bias_concat
// ---------------------------------------------------------------------------
__global__ __launch_bounds__(256) void prep_all(
    const float* __restrict__ hidden, const float* __restrict__ wq,
    const float* __restrict__ wk, const float* __restrict__ wv,
    const float* __restrict__ wo, const float* __restrict__ bq,
    const float* __restrict__ bk, const float* __restrict__ bv,
    unsigned short* __restrict__ A16, unsigned short* __restrict__ BTh,
    unsigned short* __restrict__ BTl, unsigned short* __restrict__ WoTh,
    unsigned short* __restrict__ WoTl, float* __restrict__ biasq) {
  __shared__ float sf[64][65];
  const int t = threadIdx.x;
  int blk = blockIdx.x;

  if (blk < 2048) {  // ---- cvt_half section ----
    const size_t i = ((size_t)blk * 256 + t) * 8;
    float4 a = *(const float4*)(hidden + i);
    float4 b = *(const float4*)(hidden + i + 4);
    float xs[8] = {a.x, a.y, a.z, a.w, b.x, b.y, b.z, b.w};
    us8 hv;
#pragma unroll
    for (int j = 0; j < 8; j++)
      hv[j] = __builtin_bit_cast(unsigned short, (_Float16)xs[j]);
    *(us8*)(A16 + i) = hv;
    return;
  }
  blk -= 2048;
  if (blk < 1024) {  // ---- txp_cvt sections (4 weights x 256 blocks) ----
    const int which = blk >> 8;       // 0=wq 1=wk 2=wv 3=wo
    const int sub = blk & 255;
    const float* w = which == 0 ? wq : which == 1 ? wk : which == 2 ? wv : wo;
    unsigned short* oh = which < 3 ? BTh : WoTh;
    unsigned short* ol = which < 3 ? BTl : WoTl;
    const int rowOff = which < 3 ? which * 1024 : 0;

    const int tn = (sub & 15) * 64;   // src col block
    const int tk = (sub >> 4) * 64;   // src row block
#pragma unroll
    for (int i = 0; i < 4; i++) {
      int f = i * 256 + t;
      int r = f >> 4, c4 = (f & 15) * 4;
      float4 v = *(const float4*)(w + (size_t)(tk + r) * 1024 + tn + c4);
      sf[r][c4 + 0] = v.x; sf[r][c4 + 1] = v.y;
      sf[r][c4 + 2] = v.z; sf[r][c4 + 3] = v.w;
    }
    __syncthreads();
    const int n = t >> 2;             // out row (src col)
    const int kc = (t & 3) * 16;      // k chunk
    us8 hv[2], lv[2];
#pragma unroll
    for (int half = 0; half < 2; half++) {
#pragma unroll
      for (int j = 0; j < 8; j++) {
        float x = sf[kc + half * 8 + j][n];
        _Float16 h = (_Float16)x;
        _Float16 l = (_Float16)((x - (float)h) * 1024.0f);
        hv[half][j] = __builtin_bit_cast(unsigned short, h);
        lv[half][j] = __builtin_bit_cast(unsigned short, l);
      }
    }
    size_t dst = (size_t)(rowOff + tn + n) * 1024 + tk + kc;
    *(us8*)(oh + dst) = hv[0];
    *(us8*)(oh + dst + 8) = hv[1];
    *(us8*)(ol + dst) = lv[0];
    *(us8*)(ol + dst + 8) = lv[1];
    return;
  }
  blk -= 1024;  // ---- bias_concat section (12 blocks) ----
  int i = blk * 256 + t;
  biasq[i] = i < 1024 ? bq[i] : (i < 2048 ? bk[i - 1024] : bv[i - 2048]);
}

// ---------------------------------------------------------------------------
// fp16 2-term split MFMA GEMM, 2-phase double-buffered (round-8 proven):
//   C = Ah@Bh + (Ah*2^-10)@(Bl*2^10) + bias
// 128x128 tile, BK=32, 4 waves, 16x16x32 f16 MFMA, 4x4 frags/wave.
// 2x3 LDS planes [128][32] (48 KB -> 3 blocks/CU; launch_bounds enforces
// 3 waves/SIMD so VGPR can't silently cap co-residency at 2). STAGE(t+1)
// issued BEFORE compute(t). Granule swizzle k'=k^((r>>1)&3) on global source
// + ds_read. T1 XCD swizzle; T5 setprio.
// ---------------------------------------------------------------------------
template <bool F16OUT>
__global__ __launch_bounds__(256, 3) void gemm_f16(
    const unsigned short* __restrict__ A16, const unsigned short* __restrict__ BTh,
    const unsigned short* __restrict__ BTl, const float* __restrict__ bias,
    void* __restrict__ Cout, int K, int Nn) {
  __shared__ __align__(16) unsigned short sA[2 * 128 * 32];
  __shared__ __align__(16) unsigned short sBh[2 * 128 * 32];
  __shared__ __align__(16) unsigned short sBl[2 * 128 * 32];

  const int tid = threadIdx.x;
  const int lane = tid & 63;
  const int wave = tid >> 6;
  const int wr = wave >> 1, wc = wave & 1;

  // T1 XCD-aware swizzle (nwg % 8 == 0 for both launches)
  const int gx = gridDim.x;
  const int nwg = gx * gridDim.y;
  int bid = blockIdx.y * gx + blockIdx.x;
  bid = (bid & 7) * (nwg >> 3) + (bid >> 3);
  const int bm = (bid / gx) * 128;
  const int bn = (bid % gx) * 128;

  // staging: plane = 8KB = 8 chunks of (64 lanes x 16B); wave stages chunks
  // {wave, wave+4}. Pre-swizzled global source (rule #21), linear LDS dest.
  size_t aoff[2], boff[2];
  int ldsoff[2];
#pragma unroll
  for (int c = 0; c < 2; c++) {
    const int chunk = wave + 4 * c;
    const int e = chunk * 512 + lane * 8;   // linear LDS element
    const int r = e >> 5;                   // tile row
    const int kpos = (e >> 3) & 3;          // granule position in row
    const int ksrc = kpos ^ ((r >> 1) & 3); // swizzle: source granule
    aoff[c] = (size_t)(bm + r) * K + ksrc * 8;
    boff[c] = (size_t)(bn + r) * K + ksrc * 8;
    ldsoff[c] = chunk * 512;
  }

  const int fr = lane & 15;
  const int fkg = lane >> 4;

  // ds_read offsets within one buffer
  int aroff[4], broff[4];
#pragma unroll
  for (int m = 0; m < 4; m++) {
    const int ra = wr * 64 + m * 16 + fr;
    aroff[m] = ra * 32 + ((fkg ^ ((ra >> 1) & 3)) << 3);
    const int rb = wc * 64 + m * 16 + fr;
    broff[m] = rb * 32 + ((fkg ^ ((rb >> 1) & 3)) << 3);
  }

  f32x4 acc[4][4] = {};

  const int NT = K >> 5;
  // prologue: stage tile 0 into buffer 0
#pragma unroll
  for (int c = 0; c < 2; c++) {
    load_lds16(A16 + aoff[c], sA + ldsoff[c]);
    load_lds16(BTh + boff[c], sBh + ldsoff[c]);
    load_lds16(BTl + boff[c], sBl + ldsoff[c]);
  }
  __syncthreads();  // compiler drains vmcnt(0) before barrier

  int cur = 0;
  for (int t = 0; t < NT; t++) {
    const int bo_ = cur * (128 * 32);
    const int nx_ = (cur ^ 1) * (128 * 32);
    if (t + 1 < NT) {  // issue next-tile stage BEFORE compute (overlap)
      const int k0 = (t + 1) << 5;
#pragma unroll
      for (int c = 0; c < 2; c++) {
        load_lds16(A16 + aoff[c] + k0, sA + nx_ + ldsoff[c]);
        load_lds16(BTh + boff[c] + k0, sBh + nx_ + ldsoff[c]);
        load_lds16(BTl + boff[c] + k0, sBl + nx_ + ldsoff[c]);
      }
    }
    f16x8 a[4], as_[4], bh[4], bl[4];
#pragma unroll
    for (int m = 0; m < 4; m++) {
      a[m] = *(const f16x8*)(sA + bo_ + aroff[m]);
      as_[m] = a[m] * (_Float16)0.0009765625f;  // *2^-10, exact
    }
#pragma unroll
    for (int n = 0; n < 4; n++) {
      bh[n] = *(const f16x8*)(sBh + bo_ + broff[n]);
      bl[n] = *(const f16x8*)(sBl + bo_ + broff[n]);
    }
    __builtin_amdgcn_s_setprio(1);
#pragma unroll
    for (int m = 0; m < 4; m++)
#pragma unroll
      for (int n = 0; n < 4; n++) {
        acc[m][n] = __builtin_amdgcn_mfma_f32_16x16x32_f16(a[m], bh[n], acc[m][n], 0, 0, 0);
        acc[m][n] = __builtin_amdgcn_mfma_f32_16x16x32_f16(as_[m], bl[n], acc[m][n], 0, 0, 0);
      }
    __builtin_amdgcn_s_setprio(0);
    __syncthreads();  // drains staging vmcnt + all waves' ds_reads
    cur ^= 1;
  }

  // epilogue: C/D layout col=lane&15, row=(lane>>4)*4+j
#pragma unroll
  for (int m = 0; m < 4; m++) {
    const int row = bm + wr * 64 + m * 16 + fkg * 4;
#pragma unroll
    for (int n = 0; n < 4; n++) {
      const int col = bn + wc * 64 + n * 16 + fr;
      const float bsv = bias[col];
#pragma unroll
      for (int j = 0; j < 4; j++) {
        const float v = acc[m][n][j] + bsv;
        if constexpr (F16OUT) {
          ((unsigned short*)Cout)[(size_t)(row + j) * Nn + col] =
              __builtin_bit_cast(unsigned short, (_Float16)v);
        } else {
          ((float*)Cout)[(size_t)(row + j) * Nn + col] = v;
        }
      }
    }
  }
}

// ---------------------------------------------------------------------------
// Vsum two-stage over fp16 v: part[b,chunk,d] = sum of 64 rows; then combine.
// ---------------------------------------------------------------------------
__global__ __launch_bounds__(256) void vsum_part(const unsigned short* __restrict__ v,
                                                 float* __restrict__ part) {
  const int b = blockIdx.x >> 4;
  const int chunk = blockIdx.x & 15;
  const int d4 = threadIdx.x * 4;
  const unsigned short* p =
      v + (size_t)b * N * LDQKV + (size_t)chunk * 64 * LDQKV + d4;
  float4 s = {0.f, 0.f, 0.f, 0.f};
#pragma unroll 8
  for (int n = 0; n < 64; n++) {
    us4 t = *(const us4*)(p + (size_t)n * LDQKV);
    s.x += h2f(t[0]); s.y += h2f(t[1]); s.z += h2f(t[2]); s.w += h2f(t[3]);
  }
  *(float4*)(part + (size_t)blockIdx.x * 1024 + d4) = s;
}

__global__ __launch_bounds__(256) void vsum_comb(const float* __restrict__ part,
                                                 float* __restrict__ vsum) {
  const int i = blockIdx.x * 256 + threadIdx.x;  // b*1024 + d
  const int b = i >> 10, d = i & 1023;
  float s = 0.f;
#pragma unroll
  for (int c = 0; c < 16; c++) s += part[(size_t)(b * 16 + c) * 1024 + d];
  vsum[i] = s;
}

// ---------------------------------------------------------------------------
// pass1: 256-thread blocks, 4 heads (same b,n) per block — one wave per head.
// graph row loaded once per block. Gather-dot 32 keys, closed-form softmax,
// writes p/base and the fp16 O-GEMM input plane.
// ---------------------------------------------------------------------------
__global__ __launch_bounds__(256) void attn_pass1(
    const unsigned short* __restrict__ qkv16, const float* __restrict__ vsum,
    const int* __restrict__ graph, float* __restrict__ pbuf,
    float* __restrict__ basebuf, unsigned short* __restrict__ O16) {
  const int blk = blockIdx.x;         // b*4096 + hg*1024 + n
  const int n = blk & (N - 1);
  const int hg = (blk >> 10) & 3;
  const int b = blk >> 12;
  const int wave = threadIdx.x >> 6;
  const int lane = threadIdx.x & 63;
  const int h = hg * 4 + wave;
  const int bid = (b * H + h) * N + n;  // original row id

  __shared__ float q_sh[4][DEPTH];
  __shared__ int g_sh[W];
  __shared__ float p_sh[4][W];

  const unsigned short* qrow = qkv16 + (size_t)(b * N + n) * LDQKV + h * DEPTH;
  q_sh[wave][lane] = h2f(qrow[lane]);
  if (threadIdx.x < W) g_sh[threadIdx.x] = graph[n * W + threadIdx.x];
  __syncthreads();

  const int w = lane >> 1;
  const int half = lane & 1;
  const unsigned short* krow =
      qkv16 + 1024 + (size_t)(b * N + g_sh[w]) * LDQKV + h * DEPTH + half * 32;
  float acc = 0.f;
#pragma unroll
  for (int j8 = 0; j8 < 4; j8++) {
    us8 kv = *(const us8*)(krow + j8 * 8);
    const float* qh = &q_sh[wave][half * 32 + j8 * 8];
#pragma unroll
    for (int e = 0; e < 8; e++) acc += h2f(kv[e]) * qh[e];
  }
  acc += __shfl_xor(acc, 1);
  const float dot = acc * 0.125f;

  float m = dot;
#pragma unroll
  for (int off = 2; off < 64; off <<= 1) m = fmaxf(m, __shfl_xor(m, off));
  m = fmaxf(m, 0.f);

  const float e = expf(dot - m);
  float s = e;
#pragma unroll
  for (int off = 1; off < 64; off <<= 1) s += __shfl_xor(s, off);
  s *= 0.5f;

  const float em = expf(-m);
  const float Z = (float)(N - W) * em + s;
  const float inv = 1.f / Z;
  const float base = em * inv;
  const float pw = e * inv;

  if (half == 0) p_sh[wave][w] = pw;
  __syncthreads();

  if (half == 0) pbuf[(size_t)bid * W + w] = pw;
  if (lane == 0) basebuf[bid] = base;

  const unsigned short* vbase = qkv16 + 2048;
  const int col = h * DEPTH + lane;
  float ov = base * vsum[b * D + col];
#pragma unroll 4
  for (int ww = 0; ww < W; ww++) {
    ov += (p_sh[wave][ww] - base) *
          h2f(vbase[(size_t)(b * N + g_sh[ww]) * LDQKV + col]);
  }
  _Float16 hh = (_Float16)ov;
  O16[(size_t)(b * N + n) * D + col] = __builtin_bit_cast(unsigned short, hh);
}

// ---------------------------------------------------------------------------
// attn row fill: 2 rows per block (heads h, h+8 share the graph row).
// base everywhere, p_w at graph positions. NT stores.
// ---------------------------------------------------------------------------
__global__ __launch_bounds__(256) void attn_fill2(
    const float* __restrict__ pbuf, const float* __restrict__ basebuf,
    const int* __restrict__ graph, float* __restrict__ attn) {
  const int blk = blockIdx.x;          // b*8192 + hh*1024 + n
  const int n = blk & (N - 1);
  const int hh = (blk >> 10) & 7;
  const int b = blk >> 13;
  const int t = threadIdx.x;

  __shared__ float row[2][N];
  __shared__ int g_sh[W];

  const int bid0 = (b * H + hh) * N + n;
  const int bid1 = (b * H + hh + 8) * N + n;

  if (t < W) g_sh[t] = graph[n * W + t];
  const float base0 = basebuf[bid0];
  const float base1 = basebuf[bid1];
  f32x4* row40 = (f32x4*)row[0];
  f32x4* row41 = (f32x4*)row[1];
  row40[t] = (f32x4){base0, base0, base0, base0};
  row41[t] = (f32x4){base1, base1, base1, base1};
  __syncthreads();
  if (t < 2 * W) {
    const int r = t >> 5;
    const int w = t & 31;
    const int bidr = r == 0 ? bid0 : bid1;
    row[r][g_sh[w]] = pbuf[(size_t)bidr * W + w];
  }
  __syncthreads();
  __builtin_nontemporal_store(row40[t], (f32x4*)(attn + (size_t)bid0 * N) + t);
  __builtin_nontemporal_store(row41[t], (f32x4*)(attn + (size_t)bid1 * N) + t);
}

// ---------------------------------------------------------------------------
extern "C" void kernel_launch(void* const* d_in, const int* in_sizes, int n_in,
                              void* d_out, int out_size, void* d_ws, size_t ws_size,
                              hipStream_t stream) {
  const float* hidden = (const float*)d_in[0];
  const float* wq = (const float*)d_in[1];
  const float* bq = (const float*)d_in[2];
  const float* wk = (const float*)d_in[3];
  const float* bk = (const float*)d_in[4];
  const float* wv = (const float*)d_in[5];
  const float* bv = (const float*)d_in[6];
  const float* wo = (const float*)d_in[7];
  const float* bo = (const float*)d_in[8];
  const int* graph = (const int*)d_in[9];

  float* out0 = (float*)d_out;                 // (B,N,D) final output
  float* attnp = out0 + (size_t)B * N * D;     // (B,H,N,N) — also scratch arena

  // scratch carved from attn region (64M floats; fully rewritten by attn_fill2)
  const size_t M1 = (size_t)1024 * 1024;
  unsigned short* qkv16 = (unsigned short*)attnp;              // [4096][3072] f16
  unsigned short* A16 = (unsigned short*)(attnp + 6 * M1);     // [4096][1024] f16
  unsigned short* BTh = (unsigned short*)(attnp + 8 * M1);     // [3072][1024] f16
  unsigned short* BTl = (unsigned short*)(attnp + 10 * M1);
  unsigned short* WoTh = (unsigned short*)(attnp + 12 * M1);   // [1024][1024] f16
  unsigned short* WoTl = (unsigned short*)(attnp + 13 * M1);
  unsigned short* O16 = (unsigned short*)(attnp + 14 * M1);    // [4096][1024] f16
  float* biasq = attnp + 16 * M1;                              // 3072
  float* vpart = attnp + 16 * M1 + 8192;                       // [64][1024]

  // small workspace (proven size)
  float* pbuf = (float*)d_ws;                  // B*H*N*W
  float* basebuf = pbuf + (size_t)B * H * N * W;
  float* vsumb = basebuf + (size_t)B * H * N;

  // fused converts + bias concat (one launch)
  prep_all<<<3084, 256, 0, stream>>>(hidden, wq, wk, wv, wo, bq, bk, bv,
                                     A16, BTh, BTl, WoTh, WoTl, biasq);

  // fused projection: qkv16 = f16(hidden @ [Wq | Wk | Wv] + [bq | bk | bv])
  gemm_f16<true><<<dim3(24, 32), 256, 0, stream>>>(A16, BTh, BTl, biasq,
                                                   qkv16, 1024, 3072);

  vsum_part<<<64, 256, 0, stream>>>(qkv16 + 2048, vpart);
  vsum_comb<<<16, 256, 0, stream>>>(vpart, vsumb);

  attn_pass1<<<B * 4 * N, 256, 0, stream>>>(qkv16, vsumb, graph, pbuf, basebuf,
                                            O16);

  // O-projection (fp32 out)
  gemm_f16<false><<<dim3(8, 32), 256, 0, stream>>>(O16, WoTh, WoTl, bo,
                                                   out0, 1024, 1024);

  attn_fill2<<<B * 8 * N, 256, 0, stream>>>(pbuf, basebuf, graph, attnp);
}

// Round 11
// 205.971 us; speedup vs baseline: 1.0267x; 1.0009x over previous
//
#include <hip/hip_runtime.h>
#include <hip/hip_bf16.h>

constexpr int B = 4;
constexpr int N = 1024;
constexpr int D = 1024;
constexpr int H = 16;
constexpr int DEPTH = 64;
constexpr int W = 32;
constexpr int LDQKV = 3072;   // fused q|k|v row stride (f16 elements)

typedef _Float16 f16x8 __attribute__((ext_vector_type(8)));
typedef float f32x4 __attribute__((ext_vector_type(4)));
typedef unsigned short us8 __attribute__((ext_vector_type(8)));
typedef unsigned short us4 __attribute__((ext_vector_type(4)));

__device__ __forceinline__ float h2f(unsigned short u) {
  return (float)__builtin_bit_cast(_Float16, u);
}

// ---------------------------------------------------------------------------
// async global->LDS, 16B per lane (wave-uniform LDS base, HW adds lane*16)
// ---------------------------------------------------------------------------
__device__ __forceinline__ void load_lds16(const void* g, void* l) {
  unsigned int lo = (unsigned int)(unsigned long long)l;
  __builtin_amdgcn_global_load_lds(
      (const __attribute__((address_space(1))) unsigned int*)g,
      (__attribute__((address_space(3))) unsigned int*)lo, 16, 0, 0);
}

// ---------------------------------------------------------------------------
// Fused prep: grid sections
//   [0, 2048)       cvt_half: hidden fp32 -> A16 fp16
//   [2048, 3072)    txp_cvt:  wq/wk/wv/wo -> transposed fp16 hi/lo split
//   [3072, 3084)    bias_concat
// ---------------------------------------------------------------------------
__global__ __launch_bounds__(256) void prep_all(
    const float* __restrict__ hidden, const float* __restrict__ wq,
    const float* __restrict__ wk, const float* __restrict__ wv,
    const float* __restrict__ wo, const float* __restrict__ bq,
    const float* __restrict__ bk, const float* __restrict__ bv,
    unsigned short* __restrict__ A16, unsigned short* __restrict__ BTh,
    unsigned short* __restrict__ BTl, unsigned short* __restrict__ WoTh,
    unsigned short* __restrict__ WoTl, float* __restrict__ biasq) {
  __shared__ float sf[64][65];
  const int t = threadIdx.x;
  int blk = blockIdx.x;

  if (blk < 2048) {  // ---- cvt_half section ----
    const size_t i = ((size_t)blk * 256 + t) * 8;
    float4 a = *(const float4*)(hidden + i);
    float4 b = *(const float4*)(hidden + i + 4);
    float xs[8] = {a.x, a.y, a.z, a.w, b.x, b.y, b.z, b.w};
    us8 hv;
#pragma unroll
    for (int j = 0; j < 8; j++)
      hv[j] = __builtin_bit_cast(unsigned short, (_Float16)xs[j]);
    *(us8*)(A16 + i) = hv;
    return;
  }
  blk -= 2048;
  if (blk < 1024) {  // ---- txp_cvt sections (4 weights x 256 blocks) ----
    const int which = blk >> 8;       // 0=wq 1=wk 2=wv 3=wo
    const int sub = blk & 255;
    const float* w = which == 0 ? wq : which == 1 ? wk : which == 2 ? wv : wo;
    unsigned short* oh = which < 3 ? BTh : WoTh;
    unsigned short* ol = which < 3 ? BTl : WoTl;
    const int rowOff = which < 3 ? which * 1024 : 0;

    const int tn = (sub & 15) * 64;   // src col block
    const int tk = (sub >> 4) * 64;   // src row block
#pragma unroll
    for (int i = 0; i < 4; i++) {
      int f = i * 256 + t;
      int r = f >> 4, c4 = (f & 15) * 4;
      float4 v = *(const float4*)(w + (size_t)(tk + r) * 1024 + tn + c4);
      sf[r][c4 + 0] = v.x; sf[r][c4 + 1] = v.y;
      sf[r][c4 + 2] = v.z; sf[r][c4 + 3] = v.w;
    }
    __syncthreads();
    const int n = t >> 2;             // out row (src col)
    const int kc = (t & 3) * 16;      // k chunk
    us8 hv[2], lv[2];
#pragma unroll
    for (int half = 0; half < 2; half++) {
#pragma unroll
      for (int j = 0; j < 8; j++) {
        float x = sf[kc + half * 8 + j][n];
        _Float16 h = (_Float16)x;
        _Float16 l = (_Float16)((x - (float)h) * 1024.0f);
        hv[half][j] = __builtin_bit_cast(unsigned short, h);
        lv[half][j] = __builtin_bit_cast(unsigned short, l);
      }
    }
    size_t dst = (size_t)(rowOff + tn + n) * 1024 + tk + kc;
    *(us8*)(oh + dst) = hv[0];
    *(us8*)(oh + dst + 8) = hv[1];
    *(us8*)(ol + dst) = lv[0];
    *(us8*)(ol + dst + 8) = lv[1];
    return;
  }
  blk -= 1024;  // ---- bias_concat section (12 blocks) ----
  int i = blk * 256 + t;
  biasq[i] = i < 1024 ? bq[i] : (i < 2048 ? bk[i - 1024] : bv[i - 2048]);
}

// ---------------------------------------------------------------------------
// fp16 2-term split MFMA GEMM, 2-phase double-buffered (round-8 proven):
//   C = Ah@Bh + (Ah*2^-10)@(Bl*2^10) + bias
// 128x128 tile, BK=32, 4 waves, 16x16x32 f16 MFMA, 4x4 frags/wave.
// 2x3 LDS planes [128][32] (48 KB -> 3 blocks/CU; launch_bounds enforces
// 3 waves/SIMD so VGPR can't silently cap co-residency at 2). STAGE(t+1)
// issued BEFORE compute(t). Granule swizzle k'=k^((r>>1)&3) on global source
// + ds_read. T1 XCD swizzle; T5 setprio.
// ---------------------------------------------------------------------------
template <bool F16OUT>
__global__ __launch_bounds__(256, 3) void gemm_f16(
    const unsigned short* __restrict__ A16, const unsigned short* __restrict__ BTh,
    const unsigned short* __restrict__ BTl, const float* __restrict__ bias,
    void* __restrict__ Cout, int K, int Nn) {
  __shared__ __align__(16) unsigned short sA[2 * 128 * 32];
  __shared__ __align__(16) unsigned short sBh[2 * 128 * 32];
  __shared__ __align__(16) unsigned short sBl[2 * 128 * 32];

  const int tid = threadIdx.x;
  const int lane = tid & 63;
  const int wave = tid >> 6;
  const int wr = wave >> 1, wc = wave & 1;

  // T1 XCD-aware swizzle (nwg % 8 == 0 for both launches)
  const int gx = gridDim.x;
  const int nwg = gx * gridDim.y;
  int bid = blockIdx.y * gx + blockIdx.x;
  bid = (bid & 7) * (nwg >> 3) + (bid >> 3);
  const int bm = (bid / gx) * 128;
  const int bn = (bid % gx) * 128;

  // staging: plane = 8KB = 8 chunks of (64 lanes x 16B); wave stages chunks
  // {wave, wave+4}. Pre-swizzled global source (rule #21), linear LDS dest.
  size_t aoff[2], boff[2];
  int ldsoff[2];
#pragma unroll
  for (int c = 0; c < 2; c++) {
    const int chunk = wave + 4 * c;
    const int e = chunk * 512 + lane * 8;   // linear LDS element
    const int r = e >> 5;                   // tile row
    const int kpos = (e >> 3) & 3;          // granule position in row
    const int ksrc = kpos ^ ((r >> 1) & 3); // swizzle: source granule
    aoff[c] = (size_t)(bm + r) * K + ksrc * 8;
    boff[c] = (size_t)(bn + r) * K + ksrc * 8;
    ldsoff[c] = chunk * 512;
  }

  const int fr = lane & 15;
  const int fkg = lane >> 4;

  // ds_read offsets within one buffer
  int aroff[4], broff[4];
#pragma unroll
  for (int m = 0; m < 4; m++) {
    const int ra = wr * 64 + m * 16 + fr;
    aroff[m] = ra * 32 + ((fkg ^ ((ra >> 1) & 3)) << 3);
    const int rb = wc * 64 + m * 16 + fr;
    broff[m] = rb * 32 + ((fkg ^ ((rb >> 1) & 3)) << 3);
  }

  f32x4 acc[4][4] = {};

  const int NT = K >> 5;
  // prologue: stage tile 0 into buffer 0
#pragma unroll
  for (int c = 0; c < 2; c++) {
    load_lds16(A16 + aoff[c], sA + ldsoff[c]);
    load_lds16(BTh + boff[c], sBh + ldsoff[c]);
    load_lds16(BTl + boff[c], sBl + ldsoff[c]);
  }
  __syncthreads();  // compiler drains vmcnt(0) before barrier

  int cur = 0;
  for (int t = 0; t < NT; t++) {
    const int bo_ = cur * (128 * 32);
    const int nx_ = (cur ^ 1) * (128 * 32);
    if (t + 1 < NT) {  // issue next-tile stage BEFORE compute (overlap)
      const int k0 = (t + 1) << 5;
#pragma unroll
      for (int c = 0; c < 2; c++) {
        load_lds16(A16 + aoff[c] + k0, sA + nx_ + ldsoff[c]);
        load_lds16(BTh + boff[c] + k0, sBh + nx_ + ldsoff[c]);
        load_lds16(BTl + boff[c] + k0, sBl + nx_ + ldsoff[c]);
      }
    }
    f16x8 a[4], as_[4], bh[4], bl[4];
#pragma unroll
    for (int m = 0; m < 4; m++) {
      a[m] = *(const f16x8*)(sA + bo_ + aroff[m]);
      as_[m] = a[m] * (_Float16)0.0009765625f;  // *2^-10, exact
    }
#pragma unroll
    for (int n = 0; n < 4; n++) {
      bh[n] = *(const f16x8*)(sBh + bo_ + broff[n]);
      bl[n] = *(const f16x8*)(sBl + bo_ + broff[n]);
    }
    __builtin_amdgcn_s_setprio(1);
#pragma unroll
    for (int m = 0; m < 4; m++)
#pragma unroll
      for (int n = 0; n < 4; n++) {
        acc[m][n] = __builtin_amdgcn_mfma_f32_16x16x32_f16(a[m], bh[n], acc[m][n], 0, 0, 0);
        acc[m][n] = __builtin_amdgcn_mfma_f32_16x16x32_f16(as_[m], bl[n], acc[m][n], 0, 0, 0);
      }
    __builtin_amdgcn_s_setprio(0);
    __syncthreads();  // drains staging vmcnt + all waves' ds_reads
    cur ^= 1;
  }

  // epilogue: C/D layout col=lane&15, row=(lane>>4)*4+j
#pragma unroll
  for (int m = 0; m < 4; m++) {
    const int row = bm + wr * 64 + m * 16 + fkg * 4;
#pragma unroll
    for (int n = 0; n < 4; n++) {
      const int col = bn + wc * 64 + n * 16 + fr;
      const float bsv = bias[col];
#pragma unroll
      for (int j = 0; j < 4; j++) {
        const float v = acc[m][n][j] + bsv;
        if constexpr (F16OUT) {
          ((unsigned short*)Cout)[(size_t)(row + j) * Nn + col] =
              __builtin_bit_cast(unsigned short, (_Float16)v);
        } else {
          ((float*)Cout)[(size_t)(row + j) * Nn + col] = v;
        }
      }
    }
  }
}

// ---------------------------------------------------------------------------
// Vsum two-stage over fp16 v: part[b,chunk,d] = sum of 64 rows; then combine.
// ---------------------------------------------------------------------------
__global__ __launch_bounds__(256) void vsum_part(const unsigned short* __restrict__ v,
                                                 float* __restrict__ part) {
  const int b = blockIdx.x >> 4;
  const int chunk = blockIdx.x & 15;
  const int d4 = threadIdx.x * 4;
  const unsigned short* p =
      v + (size_t)b * N * LDQKV + (size_t)chunk * 64 * LDQKV + d4;
  float4 s = {0.f, 0.f, 0.f, 0.f};
#pragma unroll 8
  for (int n = 0; n < 64; n++) {
    us4 t = *(const us4*)(p + (size_t)n * LDQKV);
    s.x += h2f(t[0]); s.y += h2f(t[1]); s.z += h2f(t[2]); s.w += h2f(t[3]);
  }
  *(float4*)(part + (size_t)blockIdx.x * 1024 + d4) = s;
}

__global__ __launch_bounds__(256) void vsum_comb(const float* __restrict__ part,
                                                 float* __restrict__ vsum) {
  const int i = blockIdx.x * 256 + threadIdx.x;  // b*1024 + d
  const int b = i >> 10, d = i & 1023;
  float s = 0.f;
#pragma unroll
  for (int c = 0; c < 16; c++) s += part[(size_t)(b * 16 + c) * 1024 + d];
  vsum[i] = s;
}

// ---------------------------------------------------------------------------
// pass1: 256-thread blocks, 4 heads (same b,n) per block — one wave per head.
// graph row loaded once per block. Gather-dot 32 keys, closed-form softmax,
// writes p/base and the fp16 O-GEMM input plane.
// ---------------------------------------------------------------------------
__global__ __launch_bounds__(256) void attn_pass1(
    const unsigned short* __restrict__ qkv16, const float* __restrict__ vsum,
    const int* __restrict__ graph, float* __restrict__ pbuf,
    float* __restrict__ basebuf, unsigned short* __restrict__ O16) {
  const int blk = blockIdx.x;         // b*4096 + hg*1024 + n
  const int n = blk & (N - 1);
  const int hg = (blk >> 10) & 3;
  const int b = blk >> 12;
  const int wave = threadIdx.x >> 6;
  const int lane = threadIdx.x & 63;
  const int h = hg * 4 + wave;
  const int bid = (b * H + h) * N + n;  // original row id

  __shared__ float q_sh[4][DEPTH];
  __shared__ int g_sh[W];
  __shared__ float p_sh[4][W];

  const unsigned short* qrow = qkv16 + (size_t)(b * N + n) * LDQKV + h * DEPTH;
  q_sh[wave][lane] = h2f(qrow[lane]);
  if (threadIdx.x < W) g_sh[threadIdx.x] = graph[n * W + threadIdx.x];
  __syncthreads();

  const int w = lane >> 1;
  const int half = lane & 1;
  const unsigned short* krow =
      qkv16 + 1024 + (size_t)(b * N + g_sh[w]) * LDQKV + h * DEPTH + half * 32;
  float acc = 0.f;
#pragma unroll
  for (int j8 = 0; j8 < 4; j8++) {
    us8 kv = *(const us8*)(krow + j8 * 8);
    const float* qh = &q_sh[wave][half * 32 + j8 * 8];
#pragma unroll
    for (int e = 0; e < 8; e++) acc += h2f(kv[e]) * qh[e];
  }
  acc += __shfl_xor(acc, 1);
  const float dot = acc * 0.125f;

  float m = dot;
#pragma unroll
  for (int off = 2; off < 64; off <<= 1) m = fmaxf(m, __shfl_xor(m, off));
  m = fmaxf(m, 0.f);

  const float e = expf(dot - m);
  float s = e;
#pragma unroll
  for (int off = 1; off < 64; off <<= 1) s += __shfl_xor(s, off);
  s *= 0.5f;

  const float em = expf(-m);
  const float Z = (float)(N - W) * em + s;
  const float inv = 1.f / Z;
  const float base = em * inv;
  const float pw = e * inv;

  if (half == 0) p_sh[wave][w] = pw;
  __syncthreads();

  if (half == 0) pbuf[(size_t)bid * W + w] = pw;
  if (lane == 0) basebuf[bid] = base;

  const unsigned short* vbase = qkv16 + 2048;
  const int col = h * DEPTH + lane;
  float ov = base * vsum[b * D + col];
#pragma unroll 4
  for (int ww = 0; ww < W; ww++) {
    ov += (p_sh[wave][ww] - base) *
          h2f(vbase[(size_t)(b * N + g_sh[ww]) * LDQKV + col]);
  }
  _Float16 hh = (_Float16)ov;
  O16[(size_t)(b * N + n) * D + col] = __builtin_bit_cast(unsigned short, hh);
}

// ---------------------------------------------------------------------------
// attn row fill: 2 rows per block (heads h, h+8 share the graph row).
// base everywhere, p_w at graph positions. NT stores.
// ---------------------------------------------------------------------------
__global__ __launch_bounds__(256) void attn_fill2(
    const float* __restrict__ pbuf, const float* __restrict__ basebuf,
    const int* __restrict__ graph, float* __restrict__ attn) {
  const int blk = blockIdx.x;          // b*8192 + hh*1024 + n
  const int n = blk & (N - 1);
  const int hh = (blk >> 10) & 7;
  const int b = blk >> 13;
  const int t = threadIdx.x;

  __shared__ float row[2][N];
  __shared__ int g_sh[W];

  const int bid0 = (b * H + hh) * N + n;
  const int bid1 = (b * H + hh + 8) * N + n;

  if (t < W) g_sh[t] = graph[n * W + t];
  const float base0 = basebuf[bid0];
  const float base1 = basebuf[bid1];
  f32x4* row40 = (f32x4*)row[0];
  f32x4* row41 = (f32x4*)row[1];
  row40[t] = (f32x4){base0, base0, base0, base0};
  row41[t] = (f32x4){base1, base1, base1, base1};
  __syncthreads();
  if (t < 2 * W) {
    const int r = t >> 5;
    const int w = t & 31;
    const int bidr = r == 0 ? bid0 : bid1;
    row[r][g_sh[w]] = pbuf[(size_t)bidr * W + w];
  }
  __syncthreads();
  __builtin_nontemporal_store(row40[t], (f32x4*)(attn + (size_t)bid0 * N) + t);
  __builtin_nontemporal_store(row41[t], (f32x4*)(attn + (size_t)bid1 * N) + t);
}

// ---------------------------------------------------------------------------
extern "C" void kernel_launch(void* const* d_in, const int* in_sizes, int n_in,
                              void* d_out, int out_size, void* d_ws, size_t ws_size,
                              hipStream_t stream) {
  const float* hidden = (const float*)d_in[0];
  const float* wq = (const float*)d_in[1];
  const float* bq = (const float*)d_in[2];
  const float* wk = (const float*)d_in[3];
  const float* bk = (const float*)d_in[4];
  const float* wv = (const float*)d_in[5];
  const float* bv = (const float*)d_in[6];
  const float* wo = (const float*)d_in[7];
  const float* bo = (const float*)d_in[8];
  const int* graph = (const int*)d_in[9];

  float* out0 = (float*)d_out;                 // (B,N,D) final output
  float* attnp = out0 + (size_t)B * N * D;     // (B,H,N,N) — also scratch arena

  // scratch carved from attn region (64M floats; fully rewritten by attn_fill2)
  const size_t M1 = (size_t)1024 * 1024;
  unsigned short* qkv16 = (unsigned short*)attnp;              // [4096][3072] f16
  unsigned short* A16 = (unsigned short*)(attnp + 6 * M1);     // [4096][1024] f16
  unsigned short* BTh = (unsigned short*)(attnp + 8 * M1);     // [3072][1024] f16
  unsigned short* BTl = (unsigned short*)(attnp + 10 * M1);
  unsigned short* WoTh = (unsigned short*)(attnp + 12 * M1);   // [1024][1024] f16
  unsigned short* WoTl = (unsigned short*)(attnp + 13 * M1);
  unsigned short* O16 = (unsigned short*)(attnp + 14 * M1);    // [4096][1024] f16
  float* biasq = attnp + 16 * M1;                              // 3072
  float* vpart = attnp + 16 * M1 + 8192;                       // [64][1024]

  // small workspace (proven size)
  float* pbuf = (float*)d_ws;                  // B*H*N*W
  float* basebuf = pbuf + (size_t)B * H * N * W;
  float* vsumb = basebuf + (size_t)B * H * N;

  // fused converts + bias concat (one launch)
  prep_all<<<3084, 256, 0, stream>>>(hidden, wq, wk, wv, wo, bq, bk, bv,
                                     A16, BTh, BTl, WoTh, WoTl, biasq);

  // fused projection: qkv16 = f16(hidden @ [Wq | Wk | Wv] + [bq | bk | bv])
  gemm_f16<true><<<dim3(24, 32), 256, 0, stream>>>(A16, BTh, BTl, biasq,
                                                   qkv16, 1024, 3072);

  vsum_part<<<64, 256, 0, stream>>>(qkv16 + 2048, vpart);
  vsum_comb<<<16, 256, 0, stream>>>(vpart, vsumb);

  attn_pass1<<<B * 4 * N, 256, 0, stream>>>(qkv16, vsumb, graph, pbuf, basebuf,
                                            O16);

  // O-projection (fp32 out)
  gemm_f16<false><<<dim3(8, 32), 256, 0, stream>>>(O16, WoTh, WoTl, bo,
                                                   out0, 1024, 1024);

  attn_fill2<<<B * 8 * N, 256, 0, stream>>>(pbuf, basebuf, graph, attnp);
}

// Round 12
// 177.361 us; speedup vs baseline: 1.1924x; 1.1613x over previous
//
#include <hip/hip_runtime.h>
#include <hip/hip_bf16.h>

constexpr int B = 4;
constexpr int N = 1024;
constexpr int D = 1024;
constexpr int H = 16;
constexpr int DEPTH = 64;
constexpr int W = 32;
constexpr int LDQKV = 3072;   // fused q|k|v row stride (f16 elements)

typedef _Float16 f16x8 __attribute__((ext_vector_type(8)));
typedef float f32x4 __attribute__((ext_vector_type(4)));
typedef unsigned short us8 __attribute__((ext_vector_type(8)));
typedef unsigned short us4 __attribute__((ext_vector_type(4)));

__device__ __forceinline__ float h2f(unsigned short u) {
  return (float)__builtin_bit_cast(_Float16, u);
}

// ---------------------------------------------------------------------------
// async global->LDS, 16B per lane (wave-uniform LDS base, HW adds lane*16)
// ---------------------------------------------------------------------------
__device__ __forceinline__ void load_lds16(const void* g, void* l) {
  unsigned int lo = (unsigned int)(unsigned long long)l;
  __builtin_amdgcn_global_load_lds(
      (const __attribute__((address_space(1))) unsigned int*)g,
      (__attribute__((address_space(3))) unsigned int*)lo, 16, 0, 0);
}

// ---------------------------------------------------------------------------
// Fused prep: grid sections
//   [0, 2048)       cvt_half: hidden fp32 -> A16 fp16
//   [2048, 3072)    txp_cvt:  wq/wk/wv/wo -> transposed fp16 (hi only)
//   [3072, 3084)    bias_concat
// ---------------------------------------------------------------------------
__global__ __launch_bounds__(256) void prep_all(
    const float* __restrict__ hidden, const float* __restrict__ wq,
    const float* __restrict__ wk, const float* __restrict__ wv,
    const float* __restrict__ wo, const float* __restrict__ bq,
    const float* __restrict__ bk, const float* __restrict__ bv,
    unsigned short* __restrict__ A16, unsigned short* __restrict__ BTh,
    unsigned short* __restrict__ WoTh, float* __restrict__ biasq) {
  __shared__ float sf[64][65];
  const int t = threadIdx.x;
  int blk = blockIdx.x;

  if (blk < 2048) {  // ---- cvt_half section ----
    const size_t i = ((size_t)blk * 256 + t) * 8;
    float4 a = *(const float4*)(hidden + i);
    float4 b = *(const float4*)(hidden + i + 4);
    float xs[8] = {a.x, a.y, a.z, a.w, b.x, b.y, b.z, b.w};
    us8 hv;
#pragma unroll
    for (int j = 0; j < 8; j++)
      hv[j] = __builtin_bit_cast(unsigned short, (_Float16)xs[j]);
    *(us8*)(A16 + i) = hv;
    return;
  }
  blk -= 2048;
  if (blk < 1024) {  // ---- txp_cvt sections (4 weights x 256 blocks) ----
    const int which = blk >> 8;       // 0=wq 1=wk 2=wv 3=wo
    const int sub = blk & 255;
    const float* w = which == 0 ? wq : which == 1 ? wk : which == 2 ? wv : wo;
    unsigned short* oh = which < 3 ? BTh : WoTh;
    const int rowOff = which < 3 ? which * 1024 : 0;

    const int tn = (sub & 15) * 64;   // src col block
    const int tk = (sub >> 4) * 64;   // src row block
#pragma unroll
    for (int i = 0; i < 4; i++) {
      int f = i * 256 + t;
      int r = f >> 4, c4 = (f & 15) * 4;
      float4 v = *(const float4*)(w + (size_t)(tk + r) * 1024 + tn + c4);
      sf[r][c4 + 0] = v.x; sf[r][c4 + 1] = v.y;
      sf[r][c4 + 2] = v.z; sf[r][c4 + 3] = v.w;
    }
    __syncthreads();
    const int n = t >> 2;             // out row (src col)
    const int kc = (t & 3) * 16;      // k chunk
    us8 hv[2];
#pragma unroll
    for (int half = 0; half < 2; half++) {
#pragma unroll
      for (int j = 0; j < 8; j++) {
        float x = sf[kc + half * 8 + j][n];
        hv[half][j] = __builtin_bit_cast(unsigned short, (_Float16)x);
      }
    }
    size_t dst = (size_t)(rowOff + tn + n) * 1024 + tk + kc;
    *(us8*)(oh + dst) = hv[0];
    *(us8*)(oh + dst + 8) = hv[1];
    return;
  }
  blk -= 1024;  // ---- bias_concat section (12 blocks) ----
  int i = blk * 256 + t;
  biasq[i] = i < 1024 ? bq[i] : (i < 2048 ? bk[i - 1024] : bv[i - 2048]);
}

// ---------------------------------------------------------------------------
// Plain fp16 MFMA GEMM (1-term), 2-phase double-buffered:
//   C = A16 @ BT^T + bias
// 128x128 tile, BK=32, 4 waves, 16x16x32 f16 MFMA, 4x4 frags/wave.
// 2x2 LDS planes [128][32] (32 KB -> 4 blocks/CU via launch_bounds(256,4)).
// STAGE(t+1) issued BEFORE compute(t). Granule swizzle k'=k^((r>>1)&3) on
// global source + ds_read (rule #21). T1 XCD swizzle; T5 setprio.
// ---------------------------------------------------------------------------
template <bool F16OUT>
__global__ __launch_bounds__(256, 4) void gemm_f16(
    const unsigned short* __restrict__ A16, const unsigned short* __restrict__ BTh,
    const float* __restrict__ bias, void* __restrict__ Cout, int K, int Nn) {
  __shared__ __align__(16) unsigned short sA[2 * 128 * 32];
  __shared__ __align__(16) unsigned short sB[2 * 128 * 32];

  const int tid = threadIdx.x;
  const int lane = tid & 63;
  const int wave = tid >> 6;
  const int wr = wave >> 1, wc = wave & 1;

  // T1 XCD-aware swizzle (nwg % 8 == 0 for both launches)
  const int gx = gridDim.x;
  const int nwg = gx * gridDim.y;
  int bid = blockIdx.y * gx + blockIdx.x;
  bid = (bid & 7) * (nwg >> 3) + (bid >> 3);
  const int bm = (bid / gx) * 128;
  const int bn = (bid % gx) * 128;

  // staging: plane = 8KB = 8 chunks of (64 lanes x 16B); wave stages chunks
  // {wave, wave+4}. Pre-swizzled global source, linear LDS dest.
  size_t aoff[2], boff[2];
  int ldsoff[2];
#pragma unroll
  for (int c = 0; c < 2; c++) {
    const int chunk = wave + 4 * c;
    const int e = chunk * 512 + lane * 8;   // linear LDS element
    const int r = e >> 5;                   // tile row
    const int kpos = (e >> 3) & 3;          // granule position in row
    const int ksrc = kpos ^ ((r >> 1) & 3); // swizzle: source granule
    aoff[c] = (size_t)(bm + r) * K + ksrc * 8;
    boff[c] = (size_t)(bn + r) * K + ksrc * 8;
    ldsoff[c] = chunk * 512;
  }

  const int fr = lane & 15;
  const int fkg = lane >> 4;

  // ds_read offsets within one buffer
  int aroff[4], broff[4];
#pragma unroll
  for (int m = 0; m < 4; m++) {
    const int ra = wr * 64 + m * 16 + fr;
    aroff[m] = ra * 32 + ((fkg ^ ((ra >> 1) & 3)) << 3);
    const int rb = wc * 64 + m * 16 + fr;
    broff[m] = rb * 32 + ((fkg ^ ((rb >> 1) & 3)) << 3);
  }

  f32x4 acc[4][4] = {};

  const int NT = K >> 5;
  // prologue: stage tile 0 into buffer 0
#pragma unroll
  for (int c = 0; c < 2; c++) {
    load_lds16(A16 + aoff[c], sA + ldsoff[c]);
    load_lds16(BTh + boff[c], sB + ldsoff[c]);
  }
  __syncthreads();  // compiler drains vmcnt(0) before barrier

  int cur = 0;
  for (int t = 0; t < NT; t++) {
    const int bo_ = cur * (128 * 32);
    const int nx_ = (cur ^ 1) * (128 * 32);
    if (t + 1 < NT) {  // issue next-tile stage BEFORE compute (overlap)
      const int k0 = (t + 1) << 5;
#pragma unroll
      for (int c = 0; c < 2; c++) {
        load_lds16(A16 + aoff[c] + k0, sA + nx_ + ldsoff[c]);
        load_lds16(BTh + boff[c] + k0, sB + nx_ + ldsoff[c]);
      }
    }
    f16x8 a[4], bh[4];
#pragma unroll
    for (int m = 0; m < 4; m++) a[m] = *(const f16x8*)(sA + bo_ + aroff[m]);
#pragma unroll
    for (int n = 0; n < 4; n++) bh[n] = *(const f16x8*)(sB + bo_ + broff[n]);
    __builtin_amdgcn_s_setprio(1);
#pragma unroll
    for (int m = 0; m < 4; m++)
#pragma unroll
      for (int n = 0; n < 4; n++)
        acc[m][n] = __builtin_amdgcn_mfma_f32_16x16x32_f16(a[m], bh[n], acc[m][n], 0, 0, 0);
    __builtin_amdgcn_s_setprio(0);
    __syncthreads();  // drains staging vmcnt + all waves' ds_reads
    cur ^= 1;
  }

  // epilogue: C/D layout col=lane&15, row=(lane>>4)*4+j
#pragma unroll
  for (int m = 0; m < 4; m++) {
    const int row = bm + wr * 64 + m * 16 + fkg * 4;
#pragma unroll
    for (int n = 0; n < 4; n++) {
      const int col = bn + wc * 64 + n * 16 + fr;
      const float bsv = bias[col];
#pragma unroll
      for (int j = 0; j < 4; j++) {
        const float v = acc[m][n][j] + bsv;
        if constexpr (F16OUT) {
          ((unsigned short*)Cout)[(size_t)(row + j) * Nn + col] =
              __builtin_bit_cast(unsigned short, (_Float16)v);
        } else {
          ((float*)Cout)[(size_t)(row + j) * Nn + col] = v;
        }
      }
    }
  }
}

// ---------------------------------------------------------------------------
// Vsum two-stage over fp16 v: part[b,chunk,d] = sum of 64 rows; then combine.
// ---------------------------------------------------------------------------
__global__ __launch_bounds__(256) void vsum_part(const unsigned short* __restrict__ v,
                                                 float* __restrict__ part) {
  const int b = blockIdx.x >> 4;
  const int chunk = blockIdx.x & 15;
  const int d4 = threadIdx.x * 4;
  const unsigned short* p =
      v + (size_t)b * N * LDQKV + (size_t)chunk * 64 * LDQKV + d4;
  float4 s = {0.f, 0.f, 0.f, 0.f};
#pragma unroll 8
  for (int n = 0; n < 64; n++) {
    us4 t = *(const us4*)(p + (size_t)n * LDQKV);
    s.x += h2f(t[0]); s.y += h2f(t[1]); s.z += h2f(t[2]); s.w += h2f(t[3]);
  }
  *(float4*)(part + (size_t)blockIdx.x * 1024 + d4) = s;
}

__global__ __launch_bounds__(256) void vsum_comb(const float* __restrict__ part,
                                                 float* __restrict__ vsum) {
  const int i = blockIdx.x * 256 + threadIdx.x;  // b*1024 + d
  const int b = i >> 10, d = i & 1023;
  float s = 0.f;
#pragma unroll
  for (int c = 0; c < 16; c++) s += part[(size_t)(b * 16 + c) * 1024 + d];
  vsum[i] = s;
}

// ---------------------------------------------------------------------------
// pass1: 256-thread blocks, 4 heads (same b,n) per block — one wave per head.
// graph row loaded once per block. Gather-dot 32 keys, closed-form softmax,
// writes p/base and the fp16 O-GEMM input plane.
// ---------------------------------------------------------------------------
__global__ __launch_bounds__(256) void attn_pass1(
    const unsigned short* __restrict__ qkv16, const float* __restrict__ vsum,
    const int* __restrict__ graph, float* __restrict__ pbuf,
    float* __restrict__ basebuf, unsigned short* __restrict__ O16) {
  const int blk = blockIdx.x;         // b*4096 + hg*1024 + n
  const int n = blk & (N - 1);
  const int hg = (blk >> 10) & 3;
  const int b = blk >> 12;
  const int wave = threadIdx.x >> 6;
  const int lane = threadIdx.x & 63;
  const int h = hg * 4 + wave;
  const int bid = (b * H + h) * N + n;  // original row id

  __shared__ float q_sh[4][DEPTH];
  __shared__ int g_sh[W];
  __shared__ float p_sh[4][W];

  const unsigned short* qrow = qkv16 + (size_t)(b * N + n) * LDQKV + h * DEPTH;
  q_sh[wave][lane] = h2f(qrow[lane]);
  if (threadIdx.x < W) g_sh[threadIdx.x] = graph[n * W + threadIdx.x];
  __syncthreads();

  const int w = lane >> 1;
  const int half = lane & 1;
  const unsigned short* krow =
      qkv16 + 1024 + (size_t)(b * N + g_sh[w]) * LDQKV + h * DEPTH + half * 32;
  float acc = 0.f;
#pragma unroll
  for (int j8 = 0; j8 < 4; j8++) {
    us8 kv = *(const us8*)(krow + j8 * 8);
    const float* qh = &q_sh[wave][half * 32 + j8 * 8];
#pragma unroll
    for (int e = 0; e < 8; e++) acc += h2f(kv[e]) * qh[e];
  }
  acc += __shfl_xor(acc, 1);
  const float dot = acc * 0.125f;

  float m = dot;
#pragma unroll
  for (int off = 2; off < 64; off <<= 1) m = fmaxf(m, __shfl_xor(m, off));
  m = fmaxf(m, 0.f);

  const float e = expf(dot - m);
  float s = e;
#pragma unroll
  for (int off = 1; off < 64; off <<= 1) s += __shfl_xor(s, off);
  s *= 0.5f;

  const float em = expf(-m);
  const float Z = (float)(N - W) * em + s;
  const float inv = 1.f / Z;
  const float base = em * inv;
  const float pw = e * inv;

  if (half == 0) p_sh[wave][w] = pw;
  __syncthreads();

  if (half == 0) pbuf[(size_t)bid * W + w] = pw;
  if (lane == 0) basebuf[bid] = base;

  const unsigned short* vbase = qkv16 + 2048;
  const int col = h * DEPTH + lane;
  float ov = base * vsum[b * D + col];
#pragma unroll 4
  for (int ww = 0; ww < W; ww++) {
    ov += (p_sh[wave][ww] - base) *
          h2f(vbase[(size_t)(b * N + g_sh[ww]) * LDQKV + col]);
  }
  _Float16 hh = (_Float16)ov;
  O16[(size_t)(b * N + n) * D + col] = __builtin_bit_cast(unsigned short, hh);
}

// ---------------------------------------------------------------------------
// attn row fill: 2 rows per block (heads h, h+8 share the graph row).
// base everywhere, p_w at graph positions. NT stores.
// ---------------------------------------------------------------------------
__global__ __launch_bounds__(256) void attn_fill2(
    const float* __restrict__ pbuf, const float* __restrict__ basebuf,
    const int* __restrict__ graph, float* __restrict__ attn) {
  const int blk = blockIdx.x;          // b*8192 + hh*1024 + n
  const int n = blk & (N - 1);
  const int hh = (blk >> 10) & 7;
  const int b = blk >> 13;
  const int t = threadIdx.x;

  __shared__ float row[2][N];
  __shared__ int g_sh[W];

  const int bid0 = (b * H + hh) * N + n;
  const int bid1 = (b * H + hh + 8) * N + n;

  if (t < W) g_sh[t] = graph[n * W + t];
  const float base0 = basebuf[bid0];
  const float base1 = basebuf[bid1];
  f32x4* row40 = (f32x4*)row[0];
  f32x4* row41 = (f32x4*)row[1];
  row40[t] = (f32x4){base0, base0, base0, base0};
  row41[t] = (f32x4){base1, base1, base1, base1};
  __syncthreads();
  if (t < 2 * W) {
    const int r = t >> 5;
    const int w = t & 31;
    const int bidr = r == 0 ? bid0 : bid1;
    row[r][g_sh[w]] = pbuf[(size_t)bidr * W + w];
  }
  __syncthreads();
  __builtin_nontemporal_store(row40[t], (f32x4*)(attn + (size_t)bid0 * N) + t);
  __builtin_nontemporal_store(row41[t], (f32x4*)(attn + (size_t)bid1 * N) + t);
}

// ---------------------------------------------------------------------------
extern "C" void kernel_launch(void* const* d_in, const int* in_sizes, int n_in,
                              void* d_out, int out_size, void* d_ws, size_t ws_size,
                              hipStream_t stream) {
  const float* hidden = (const float*)d_in[0];
  const float* wq = (const float*)d_in[1];
  const float* bq = (const float*)d_in[2];
  const float* wk = (const float*)d_in[3];
  const float* bk = (const float*)d_in[4];
  const float* wv = (const float*)d_in[5];
  const float* bv = (const float*)d_in[6];
  const float* wo = (const float*)d_in[7];
  const float* bo = (const float*)d_in[8];
  const int* graph = (const int*)d_in[9];

  float* out0 = (float*)d_out;                 // (B,N,D) final output
  float* attnp = out0 + (size_t)B * N * D;     // (B,H,N,N) — also scratch arena

  // scratch carved from attn region (64M floats; fully rewritten by attn_fill2)
  const size_t M1 = (size_t)1024 * 1024;
  unsigned short* qkv16 = (unsigned short*)attnp;              // [4096][3072] f16
  unsigned short* A16 = (unsigned short*)(attnp + 6 * M1);     // [4096][1024] f16
  unsigned short* BTh = (unsigned short*)(attnp + 8 * M1);     // [3072][1024] f16
  unsigned short* WoTh = (unsigned short*)(attnp + 10 * M1);   // [1024][1024] f16
  unsigned short* O16 = (unsigned short*)(attnp + 11 * M1);    // [4096][1024] f16
  float* biasq = attnp + 13 * M1;                              // 3072
  float* vpart = attnp + 13 * M1 + 8192;                       // [64][1024]

  // small workspace (proven size)
  float* pbuf = (float*)d_ws;                  // B*H*N*W
  float* basebuf = pbuf + (size_t)B * H * N * W;
  float* vsumb = basebuf + (size_t)B * H * N;

  // fused converts + bias concat (one launch)
  prep_all<<<3084, 256, 0, stream>>>(hidden, wq, wk, wv, wo, bq, bk, bv,
                                     A16, BTh, WoTh, biasq);

  // fused projection: qkv16 = f16(hidden @ [Wq | Wk | Wv] + [bq | bk | bv])
  gemm_f16<true><<<dim3(24, 32), 256, 0, stream>>>(A16, BTh, biasq,
                                                   qkv16, 1024, 3072);

  vsum_part<<<64, 256, 0, stream>>>(qkv16 + 2048, vpart);
  vsum_comb<<<16, 256, 0, stream>>>(vpart, vsumb);

  attn_pass1<<<B * 4 * N, 256, 0, stream>>>(qkv16, vsumb, graph, pbuf, basebuf,
                                            O16);

  // O-projection (fp32 out)
  gemm_f16<false><<<dim3(8, 32), 256, 0, stream>>>(O16, WoTh, bo,
                                                   out0, 1024, 1024);

  attn_fill2<<<B * 8 * N, 256, 0, stream>>>(pbuf, basebuf, graph, attnp);
}

// Round 13
// 175.694 us; speedup vs baseline: 1.2037x; 1.0095x over previous
//
#include <hip/hip_runtime.h>
#include <hip/hip_bf16.h>

constexpr int B = 4;
constexpr int N = 1024;
constexpr int D = 1024;
constexpr int H = 16;
constexpr int DEPTH = 64;
constexpr int W = 32;
constexpr int LDQKV = 3072;   // fused q|k|v row stride (f16 elements)

typedef _Float16 f16x8 __attribute__((ext_vector_type(8)));
typedef float f32x4 __attribute__((ext_vector_type(4)));
typedef unsigned short us8 __attribute__((ext_vector_type(8)));
typedef unsigned short us4 __attribute__((ext_vector_type(4)));

__device__ __forceinline__ float h2f(unsigned short u) {
  return (float)__builtin_bit_cast(_Float16, u);
}

// ---------------------------------------------------------------------------
// async global->LDS, 16B per lane (wave-uniform LDS base, HW adds lane*16)
// ---------------------------------------------------------------------------
__device__ __forceinline__ void load_lds16(const void* g, void* l) {
  unsigned int lo = (unsigned int)(unsigned long long)l;
  __builtin_amdgcn_global_load_lds(
      (const __attribute__((address_space(1))) unsigned int*)g,
      (__attribute__((address_space(3))) unsigned int*)lo, 16, 0, 0);
}

// ---------------------------------------------------------------------------
// Fused prep: grid sections
//   [0, 2048)       cvt_half: hidden fp32 -> A16 fp16
//   [2048, 3072)    txp_cvt:  wq/wk/wv/wo -> transposed fp16 (hi only)
//   [3072, 3084)    bias_concat
// ---------------------------------------------------------------------------
__global__ __launch_bounds__(256) void prep_all(
    const float* __restrict__ hidden, const float* __restrict__ wq,
    const float* __restrict__ wk, const float* __restrict__ wv,
    const float* __restrict__ wo, const float* __restrict__ bq,
    const float* __restrict__ bk, const float* __restrict__ bv,
    unsigned short* __restrict__ A16, unsigned short* __restrict__ BTh,
    unsigned short* __restrict__ WoTh, float* __restrict__ biasq) {
  __shared__ float sf[64][65];
  const int t = threadIdx.x;
  int blk = blockIdx.x;

  if (blk < 2048) {  // ---- cvt_half section ----
    const size_t i = ((size_t)blk * 256 + t) * 8;
    float4 a = *(const float4*)(hidden + i);
    float4 b = *(const float4*)(hidden + i + 4);
    float xs[8] = {a.x, a.y, a.z, a.w, b.x, b.y, b.z, b.w};
    us8 hv;
#pragma unroll
    for (int j = 0; j < 8; j++)
      hv[j] = __builtin_bit_cast(unsigned short, (_Float16)xs[j]);
    *(us8*)(A16 + i) = hv;
    return;
  }
  blk -= 2048;
  if (blk < 1024) {  // ---- txp_cvt sections (4 weights x 256 blocks) ----
    const int which = blk >> 8;       // 0=wq 1=wk 2=wv 3=wo
    const int sub = blk & 255;
    const float* w = which == 0 ? wq : which == 1 ? wk : which == 2 ? wv : wo;
    unsigned short* oh = which < 3 ? BTh : WoTh;
    const int rowOff = which < 3 ? which * 1024 : 0;

    const int tn = (sub & 15) * 64;   // src col block
    const int tk = (sub >> 4) * 64;   // src row block
#pragma unroll
    for (int i = 0; i < 4; i++) {
      int f = i * 256 + t;
      int r = f >> 4, c4 = (f & 15) * 4;
      float4 v = *(const float4*)(w + (size_t)(tk + r) * 1024 + tn + c4);
      sf[r][c4 + 0] = v.x; sf[r][c4 + 1] = v.y;
      sf[r][c4 + 2] = v.z; sf[r][c4 + 3] = v.w;
    }
    __syncthreads();
    const int n = t >> 2;             // out row (src col)
    const int kc = (t & 3) * 16;      // k chunk
    us8 hv[2];
#pragma unroll
    for (int half = 0; half < 2; half++) {
#pragma unroll
      for (int j = 0; j < 8; j++) {
        float x = sf[kc + half * 8 + j][n];
        hv[half][j] = __builtin_bit_cast(unsigned short, (_Float16)x);
      }
    }
    size_t dst = (size_t)(rowOff + tn + n) * 1024 + tk + kc;
    *(us8*)(oh + dst) = hv[0];
    *(us8*)(oh + dst + 8) = hv[1];
    return;
  }
  blk -= 1024;  // ---- bias_concat section (12 blocks) ----
  int i = blk * 256 + t;
  biasq[i] = i < 1024 ? bq[i] : (i < 2048 ? bk[i - 1024] : bv[i - 2048]);
}

// ---------------------------------------------------------------------------
// QKV GEMM: 128x256 tile, wave = 64x128 output (acc 4x8) — raises MFMA:LDS
// ratio from 80:96 to 160:144 cyc (LDS-read-bound -> MFMA-bound).
// BK=32, 4 waves, 2-phase dbuf (48 KB LDS), f16 out.
// Granule swizzle k'=k^((r>>1)&3) on global source + ds_read.
// T1 XCD swizzle (384 blocks %8==0); T5 setprio. VGPR ~210 -> 2 blocks/CU.
// ---------------------------------------------------------------------------
__global__ __launch_bounds__(256, 2) void gemm_qkv(
    const unsigned short* __restrict__ A16, const unsigned short* __restrict__ BTh,
    const float* __restrict__ bias, unsigned short* __restrict__ Cout,
    int K, int Nn) {
  __shared__ __align__(16) unsigned short sA[2 * 128 * 32];
  __shared__ __align__(16) unsigned short sB[2 * 256 * 32];

  const int tid = threadIdx.x;
  const int lane = tid & 63;
  const int wave = tid >> 6;
  const int wr = wave >> 1, wc = wave & 1;

  // T1 XCD-aware swizzle
  const int gx = gridDim.x;
  const int nwg = gx * gridDim.y;
  int bid = blockIdx.y * gx + blockIdx.x;
  bid = (bid & 7) * (nwg >> 3) + (bid >> 3);
  const int bm = (bid / gx) * 128;
  const int bn = (bid % gx) * 256;

  // A staging: 8KB = 8 chunks; wave stages {wave, wave+4}
  size_t aoff[2];
  int ldsA[2];
#pragma unroll
  for (int c = 0; c < 2; c++) {
    const int chunk = wave + 4 * c;
    const int e = chunk * 512 + lane * 8;
    const int r = e >> 5;
    const int kpos = (e >> 3) & 3;
    const int ksrc = kpos ^ ((r >> 1) & 3);
    aoff[c] = (size_t)(bm + r) * K + ksrc * 8;
    ldsA[c] = chunk * 512;
  }
  // B staging: 16KB = 16 chunks; wave stages {wave, wave+4, wave+8, wave+12}
  size_t boff[4];
  int ldsB[4];
#pragma unroll
  for (int c = 0; c < 4; c++) {
    const int chunk = wave + 4 * c;
    const int e = chunk * 512 + lane * 8;
    const int r = e >> 5;                   // 0..255
    const int kpos = (e >> 3) & 3;
    const int ksrc = kpos ^ ((r >> 1) & 3);
    boff[c] = (size_t)(bn + r) * K + ksrc * 8;
    ldsB[c] = chunk * 512;
  }

  const int fr = lane & 15;
  const int fkg = lane >> 4;

  int aroff[4], broff[8];
#pragma unroll
  for (int m = 0; m < 4; m++) {
    const int ra = wr * 64 + m * 16 + fr;
    aroff[m] = ra * 32 + ((fkg ^ ((ra >> 1) & 3)) << 3);
  }
#pragma unroll
  for (int n = 0; n < 8; n++) {
    const int rb = wc * 128 + n * 16 + fr;
    broff[n] = rb * 32 + ((fkg ^ ((rb >> 1) & 3)) << 3);
  }

  f32x4 acc[4][8] = {};

  const int NT = K >> 5;
  // prologue: stage tile 0 into buffer 0
#pragma unroll
  for (int c = 0; c < 2; c++) load_lds16(A16 + aoff[c], sA + ldsA[c]);
#pragma unroll
  for (int c = 0; c < 4; c++) load_lds16(BTh + boff[c], sB + ldsB[c]);
  __syncthreads();

  int cur = 0;
  for (int t = 0; t < NT; t++) {
    const int boA = cur * (128 * 32);
    const int boB = cur * (256 * 32);
    const int nxA = (cur ^ 1) * (128 * 32);
    const int nxB = (cur ^ 1) * (256 * 32);
    if (t + 1 < NT) {  // issue next-tile stage BEFORE compute
      const int k0 = (t + 1) << 5;
#pragma unroll
      for (int c = 0; c < 2; c++) load_lds16(A16 + aoff[c] + k0, sA + nxA + ldsA[c]);
#pragma unroll
      for (int c = 0; c < 4; c++) load_lds16(BTh + boff[c] + k0, sB + nxB + ldsB[c]);
    }
    f16x8 a[4], bh[8];
#pragma unroll
    for (int m = 0; m < 4; m++) a[m] = *(const f16x8*)(sA + boA + aroff[m]);
#pragma unroll
    for (int n = 0; n < 8; n++) bh[n] = *(const f16x8*)(sB + boB + broff[n]);
    __builtin_amdgcn_s_setprio(1);
#pragma unroll
    for (int m = 0; m < 4; m++)
#pragma unroll
      for (int n = 0; n < 8; n++)
        acc[m][n] = __builtin_amdgcn_mfma_f32_16x16x32_f16(a[m], bh[n], acc[m][n], 0, 0, 0);
    __builtin_amdgcn_s_setprio(0);
    __syncthreads();
    cur ^= 1;
  }

  // epilogue: C/D layout col=lane&15, row=(lane>>4)*4+j; f16 out
#pragma unroll
  for (int m = 0; m < 4; m++) {
    const int row = bm + wr * 64 + m * 16 + fkg * 4;
#pragma unroll
    for (int n = 0; n < 8; n++) {
      const int col = bn + wc * 128 + n * 16 + fr;
      const float bsv = bias[col];
#pragma unroll
      for (int j = 0; j < 4; j++) {
        const float v = acc[m][n][j] + bsv;
        Cout[(size_t)(row + j) * Nn + col] =
            __builtin_bit_cast(unsigned short, (_Float16)v);
      }
    }
  }
}

// ---------------------------------------------------------------------------
// O-projection GEMM (round-12 proven 128x128 structure, fp32 out):
// 2-phase dbuf, BK=32, 4 waves, acc 4x4, 32 KB LDS -> 4 blocks/CU.
// ---------------------------------------------------------------------------
__global__ __launch_bounds__(256, 4) void gemm_o(
    const unsigned short* __restrict__ A16, const unsigned short* __restrict__ BTh,
    const float* __restrict__ bias, float* __restrict__ Cout, int K, int Nn) {
  __shared__ __align__(16) unsigned short sA[2 * 128 * 32];
  __shared__ __align__(16) unsigned short sB[2 * 128 * 32];

  const int tid = threadIdx.x;
  const int lane = tid & 63;
  const int wave = tid >> 6;
  const int wr = wave >> 1, wc = wave & 1;

  const int gx = gridDim.x;
  const int nwg = gx * gridDim.y;
  int bid = blockIdx.y * gx + blockIdx.x;
  bid = (bid & 7) * (nwg >> 3) + (bid >> 3);
  const int bm = (bid / gx) * 128;
  const int bn = (bid % gx) * 128;

  size_t aoff[2], boff[2];
  int ldsoff[2];
#pragma unroll
  for (int c = 0; c < 2; c++) {
    const int chunk = wave + 4 * c;
    const int e = chunk * 512 + lane * 8;
    const int r = e >> 5;
    const int kpos = (e >> 3) & 3;
    const int ksrc = kpos ^ ((r >> 1) & 3);
    aoff[c] = (size_t)(bm + r) * K + ksrc * 8;
    boff[c] = (size_t)(bn + r) * K + ksrc * 8;
    ldsoff[c] = chunk * 512;
  }

  const int fr = lane & 15;
  const int fkg = lane >> 4;

  int aroff[4], broff[4];
#pragma unroll
  for (int m = 0; m < 4; m++) {
    const int ra = wr * 64 + m * 16 + fr;
    aroff[m] = ra * 32 + ((fkg ^ ((ra >> 1) & 3)) << 3);
    const int rb = wc * 64 + m * 16 + fr;
    broff[m] = rb * 32 + ((fkg ^ ((rb >> 1) & 3)) << 3);
  }

  f32x4 acc[4][4] = {};

  const int NT = K >> 5;
#pragma unroll
  for (int c = 0; c < 2; c++) {
    load_lds16(A16 + aoff[c], sA + ldsoff[c]);
    load_lds16(BTh + boff[c], sB + ldsoff[c]);
  }
  __syncthreads();

  int cur = 0;
  for (int t = 0; t < NT; t++) {
    const int bo_ = cur * (128 * 32);
    const int nx_ = (cur ^ 1) * (128 * 32);
    if (t + 1 < NT) {
      const int k0 = (t + 1) << 5;
#pragma unroll
      for (int c = 0; c < 2; c++) {
        load_lds16(A16 + aoff[c] + k0, sA + nx_ + ldsoff[c]);
        load_lds16(BTh + boff[c] + k0, sB + nx_ + ldsoff[c]);
      }
    }
    f16x8 a[4], bh[4];
#pragma unroll
    for (int m = 0; m < 4; m++) a[m] = *(const f16x8*)(sA + bo_ + aroff[m]);
#pragma unroll
    for (int n = 0; n < 4; n++) bh[n] = *(const f16x8*)(sB + bo_ + broff[n]);
    __builtin_amdgcn_s_setprio(1);
#pragma unroll
    for (int m = 0; m < 4; m++)
#pragma unroll
      for (int n = 0; n < 4; n++)
        acc[m][n] = __builtin_amdgcn_mfma_f32_16x16x32_f16(a[m], bh[n], acc[m][n], 0, 0, 0);
    __builtin_amdgcn_s_setprio(0);
    __syncthreads();
    cur ^= 1;
  }

#pragma unroll
  for (int m = 0; m < 4; m++) {
    const int row = bm + wr * 64 + m * 16 + fkg * 4;
#pragma unroll
    for (int n = 0; n < 4; n++) {
      const int col = bn + wc * 64 + n * 16 + fr;
      const float bsv = bias[col];
#pragma unroll
      for (int j = 0; j < 4; j++)
        Cout[(size_t)(row + j) * Nn + col] = acc[m][n][j] + bsv;
    }
  }
}

// ---------------------------------------------------------------------------
// Vsum two-stage over fp16 v: part[b,chunk,d] = sum of 64 rows; then combine.
// ---------------------------------------------------------------------------
__global__ __launch_bounds__(256) void vsum_part(const unsigned short* __restrict__ v,
                                                 float* __restrict__ part) {
  const int b = blockIdx.x >> 4;
  const int chunk = blockIdx.x & 15;
  const int d4 = threadIdx.x * 4;
  const unsigned short* p =
      v + (size_t)b * N * LDQKV + (size_t)chunk * 64 * LDQKV + d4;
  float4 s = {0.f, 0.f, 0.f, 0.f};
#pragma unroll 8
  for (int n = 0; n < 64; n++) {
    us4 t = *(const us4*)(p + (size_t)n * LDQKV);
    s.x += h2f(t[0]); s.y += h2f(t[1]); s.z += h2f(t[2]); s.w += h2f(t[3]);
  }
  *(float4*)(part + (size_t)blockIdx.x * 1024 + d4) = s;
}

__global__ __launch_bounds__(256) void vsum_comb(const float* __restrict__ part,
                                                 float* __restrict__ vsum) {
  const int i = blockIdx.x * 256 + threadIdx.x;  // b*1024 + d
  const int b = i >> 10, d = i & 1023;
  float s = 0.f;
#pragma unroll
  for (int c = 0; c < 16; c++) s += part[(size_t)(b * 16 + c) * 1024 + d];
  vsum[i] = s;
}

// ---------------------------------------------------------------------------
// pass1: 256-thread blocks, 4 heads (same b,n) per block — one wave per head.
// graph row loaded once per block. Gather-dot 32 keys, closed-form softmax,
// writes p/base and the fp16 O-GEMM input plane.
// ---------------------------------------------------------------------------
__global__ __launch_bounds__(256) void attn_pass1(
    const unsigned short* __restrict__ qkv16, const float* __restrict__ vsum,
    const int* __restrict__ graph, float* __restrict__ pbuf,
    float* __restrict__ basebuf, unsigned short* __restrict__ O16) {
  const int blk = blockIdx.x;         // b*4096 + hg*1024 + n
  const int n = blk & (N - 1);
  const int hg = (blk >> 10) & 3;
  const int b = blk >> 12;
  const int wave = threadIdx.x >> 6;
  const int lane = threadIdx.x & 63;
  const int h = hg * 4 + wave;
  const int bid = (b * H + h) * N + n;  // original row id

  __shared__ float q_sh[4][DEPTH];
  __shared__ int g_sh[W];
  __shared__ float p_sh[4][W];

  const unsigned short* qrow = qkv16 + (size_t)(b * N + n) * LDQKV + h * DEPTH;
  q_sh[wave][lane] = h2f(qrow[lane]);
  if (threadIdx.x < W) g_sh[threadIdx.x] = graph[n * W + threadIdx.x];
  __syncthreads();

  const int w = lane >> 1;
  const int half = lane & 1;
  const unsigned short* krow =
      qkv16 + 1024 + (size_t)(b * N + g_sh[w]) * LDQKV + h * DEPTH + half * 32;
  float acc = 0.f;
#pragma unroll
  for (int j8 = 0; j8 < 4; j8++) {
    us8 kv = *(const us8*)(krow + j8 * 8);
    const float* qh = &q_sh[wave][half * 32 + j8 * 8];
#pragma unroll
    for (int e = 0; e < 8; e++) acc += h2f(kv[e]) * qh[e];
  }
  acc += __shfl_xor(acc, 1);
  const float dot = acc * 0.125f;

  float m = dot;
#pragma unroll
  for (int off = 2; off < 64; off <<= 1) m = fmaxf(m, __shfl_xor(m, off));
  m = fmaxf(m, 0.f);

  const float e = expf(dot - m);
  float s = e;
#pragma unroll
  for (int off = 1; off < 64; off <<= 1) s += __shfl_xor(s, off);
  s *= 0.5f;

  const float em = expf(-m);
  const float Z = (float)(N - W) * em + s;
  const float inv = 1.f / Z;
  const float base = em * inv;
  const float pw = e * inv;

  if (half == 0) p_sh[wave][w] = pw;
  __syncthreads();

  if (half == 0) pbuf[(size_t)bid * W + w] = pw;
  if (lane == 0) basebuf[bid] = base;

  const unsigned short* vbase = qkv16 + 2048;
  const int col = h * DEPTH + lane;
  float ov = base * vsum[b * D + col];
#pragma unroll 4
  for (int ww = 0; ww < W; ww++) {
    ov += (p_sh[wave][ww] - base) *
          h2f(vbase[(size_t)(b * N + g_sh[ww]) * LDQKV + col]);
  }
  _Float16 hh = (_Float16)ov;
  O16[(size_t)(b * N + n) * D + col] = __builtin_bit_cast(unsigned short, hh);
}

// ---------------------------------------------------------------------------
// attn row fill: 2 rows per block (heads h, h+8 share the graph row).
// base everywhere, p_w at graph positions. NT stores.
// ---------------------------------------------------------------------------
__global__ __launch_bounds__(256) void attn_fill2(
    const float* __restrict__ pbuf, const float* __restrict__ basebuf,
    const int* __restrict__ graph, float* __restrict__ attn) {
  const int blk = blockIdx.x;          // b*8192 + hh*1024 + n
  const int n = blk & (N - 1);
  const int hh = (blk >> 10) & 7;
  const int b = blk >> 13;
  const int t = threadIdx.x;

  __shared__ float row[2][N];
  __shared__ int g_sh[W];

  const int bid0 = (b * H + hh) * N + n;
  const int bid1 = (b * H + hh + 8) * N + n;

  if (t < W) g_sh[t] = graph[n * W + t];
  const float base0 = basebuf[bid0];
  const float base1 = basebuf[bid1];
  f32x4* row40 = (f32x4*)row[0];
  f32x4* row41 = (f32x4*)row[1];
  row40[t] = (f32x4){base0, base0, base0, base0};
  row41[t] = (f32x4){base1, base1, base1, base1};
  __syncthreads();
  if (t < 2 * W) {
    const int r = t >> 5;
    const int w = t & 31;
    const int bidr = r == 0 ? bid0 : bid1;
    row[r][g_sh[w]] = pbuf[(size_t)bidr * W + w];
  }
  __syncthreads();
  __builtin_nontemporal_store(row40[t], (f32x4*)(attn + (size_t)bid0 * N) + t);
  __builtin_nontemporal_store(row41[t], (f32x4*)(attn + (size_t)bid1 * N) + t);
}

// ---------------------------------------------------------------------------
extern "C" void kernel_launch(void* const* d_in, const int* in_sizes, int n_in,
                              void* d_out, int out_size, void* d_ws, size_t ws_size,
                              hipStream_t stream) {
  const float* hidden = (const float*)d_in[0];
  const float* wq = (const float*)d_in[1];
  const float* bq = (const float*)d_in[2];
  const float* wk = (const float*)d_in[3];
  const float* bk = (const float*)d_in[4];
  const float* wv = (const float*)d_in[5];
  const float* bv = (const float*)d_in[6];
  const float* wo = (const float*)d_in[7];
  const float* bo = (const float*)d_in[8];
  const int* graph = (const int*)d_in[9];

  float* out0 = (float*)d_out;                 // (B,N,D) final output
  float* attnp = out0 + (size_t)B * N * D;     // (B,H,N,N) — also scratch arena

  // scratch carved from attn region (64M floats; fully rewritten by attn_fill2)
  const size_t M1 = (size_t)1024 * 1024;
  unsigned short* qkv16 = (unsigned short*)attnp;              // [4096][3072] f16
  unsigned short* A16 = (unsigned short*)(attnp + 6 * M1);     // [4096][1024] f16
  unsigned short* BTh = (unsigned short*)(attnp + 8 * M1);     // [3072][1024] f16
  unsigned short* WoTh = (unsigned short*)(attnp + 10 * M1);   // [1024][1024] f16
  unsigned short* O16 = (unsigned short*)(attnp + 11 * M1);    // [4096][1024] f16
  float* biasq = attnp + 13 * M1;                              // 3072
  float* vpart = attnp + 13 * M1 + 8192;                       // [64][1024]

  // small workspace (proven size)
  float* pbuf = (float*)d_ws;                  // B*H*N*W
  float* basebuf = pbuf + (size_t)B * H * N * W;
  float* vsumb = basebuf + (size_t)B * H * N;

  // fused converts + bias concat (one launch)
  prep_all<<<3084, 256, 0, stream>>>(hidden, wq, wk, wv, wo, bq, bk, bv,
                                     A16, BTh, WoTh, biasq);

  // fused projection: qkv16 = f16(hidden @ [Wq | Wk | Wv] + [bq | bk | bv])
  // 128x256 tile: grid (3072/256, 4096/128) = (12, 32) = 384 blocks
  gemm_qkv<<<dim3(12, 32), 256, 0, stream>>>(A16, BTh, biasq, qkv16,
                                             1024, 3072);

  vsum_part<<<64, 256, 0, stream>>>(qkv16 + 2048, vpart);
  vsum_comb<<<16, 256, 0, stream>>>(vpart, vsumb);

  attn_pass1<<<B * 4 * N, 256, 0, stream>>>(qkv16, vsumb, graph, pbuf, basebuf,
                                            O16);

  // O-projection (fp32 out, 128x128 tile: grid (8, 32) = 256 blocks)
  gemm_o<<<dim3(8, 32), 256, 0, stream>>>(O16, WoTh, bo, out0, 1024, 1024);

  attn_fill2<<<B * 8 * N, 256, 0, stream>>>(pbuf, basebuf, graph, attnp);
}

// Round 15
// 154.412 us; speedup vs baseline: 1.3696x; 1.1378x over previous
//
#include <hip/hip_runtime.h>
#include <hip/hip_bf16.h>

constexpr int B = 4;
constexpr int N = 1024;
constexpr int D = 1024;
constexpr int H = 16;
constexpr int DEPTH = 64;
constexpr int W = 32;
constexpr int LDQKV = 3072;   // fused q|k|v row stride (f16 elements)
constexpr int SROWS = 12288;  // attn rows [0,SROWS) hold scratch during pass1

typedef _Float16 f16x8 __attribute__((ext_vector_type(8)));
typedef float f32x4 __attribute__((ext_vector_type(4)));
typedef unsigned short us8 __attribute__((ext_vector_type(8)));
typedef unsigned short us4 __attribute__((ext_vector_type(4)));

__device__ __forceinline__ float h2f(unsigned short u) {
  return (float)__builtin_bit_cast(_Float16, u);
}

// ---------------------------------------------------------------------------
// async global->LDS, 16B per lane (wave-uniform LDS base, HW adds lane*16)
// ---------------------------------------------------------------------------
__device__ __forceinline__ void load_lds16(const void* g, void* l) {
  unsigned int lo = (unsigned int)(unsigned long long)l;
  __builtin_amdgcn_global_load_lds(
      (const __attribute__((address_space(1))) unsigned int*)g,
      (__attribute__((address_space(3))) unsigned int*)lo, 16, 0, 0);
}

// ---------------------------------------------------------------------------
// Fused prep: grid sections
//   [0, 2048)       cvt_half: hidden fp32 -> A16 fp16
//   [2048, 3072)    txp_cvt:  wq/wk/wv/wo -> transposed fp16 (hi only)
//   [3072, 3084)    bias_concat
// ---------------------------------------------------------------------------
__global__ __launch_bounds__(256) void prep_all(
    const float* __restrict__ hidden, const float* __restrict__ wq,
    const float* __restrict__ wk, const float* __restrict__ wv,
    const float* __restrict__ wo, const float* __restrict__ bq,
    const float* __restrict__ bk, const float* __restrict__ bv,
    unsigned short* __restrict__ A16, unsigned short* __restrict__ BTh,
    unsigned short* __restrict__ WoTh, float* __restrict__ biasq) {
  __shared__ float sf[64][65];
  const int t = threadIdx.x;
  int blk = blockIdx.x;

  if (blk < 2048) {  // ---- cvt_half section ----
    const size_t i = ((size_t)blk * 256 + t) * 8;
    float4 a = *(const float4*)(hidden + i);
    float4 b = *(const float4*)(hidden + i + 4);
    float xs[8] = {a.x, a.y, a.z, a.w, b.x, b.y, b.z, b.w};
    us8 hv;
#pragma unroll
    for (int j = 0; j < 8; j++)
      hv[j] = __builtin_bit_cast(unsigned short, (_Float16)xs[j]);
    *(us8*)(A16 + i) = hv;
    return;
  }
  blk -= 2048;
  if (blk < 1024) {  // ---- txp_cvt sections (4 weights x 256 blocks) ----
    const int which = blk >> 8;       // 0=wq 1=wk 2=wv 3=wo
    const int sub = blk & 255;
    const float* w = which == 0 ? wq : which == 1 ? wk : which == 2 ? wv : wo;
    unsigned short* oh = which < 3 ? BTh : WoTh;
    const int rowOff = which < 3 ? which * 1024 : 0;

    const int tn = (sub & 15) * 64;   // src col block
    const int tk = (sub >> 4) * 64;   // src row block
#pragma unroll
    for (int i = 0; i < 4; i++) {
      int f = i * 256 + t;
      int r = f >> 4, c4 = (f & 15) * 4;
      float4 v = *(const float4*)(w + (size_t)(tk + r) * 1024 + tn + c4);
      sf[r][c4 + 0] = v.x; sf[r][c4 + 1] = v.y;
      sf[r][c4 + 2] = v.z; sf[r][c4 + 3] = v.w;
    }
    __syncthreads();
    const int n = t >> 2;             // out row (src col)
    const int kc = (t & 3) * 16;      // k chunk
    us8 hv[2];
#pragma unroll
    for (int half = 0; half < 2; half++) {
#pragma unroll
      for (int j = 0; j < 8; j++) {
        float x = sf[kc + half * 8 + j][n];
        hv[half][j] = __builtin_bit_cast(unsigned short, (_Float16)x);
      }
    }
    size_t dst = (size_t)(rowOff + tn + n) * 1024 + tk + kc;
    *(us8*)(oh + dst) = hv[0];
    *(us8*)(oh + dst + 8) = hv[1];
    return;
  }
  blk -= 1024;  // ---- bias_concat section (12 blocks) ----
  int i = blk * 256 + t;
  biasq[i] = i < 1024 ? bq[i] : (i < 2048 ? bk[i - 1024] : bv[i - 2048]);
}

// ---------------------------------------------------------------------------
// QKV GEMM: 128x256 tile, wave = 64x128 (acc 4x8). BK=32, 4 waves,
// 2-phase dbuf (48 KB LDS), f16 out. Granule swizzle k'=k^((r>>1)&3) on
// global source + ds_read. T1 XCD swizzle; T5 setprio.
// ---------------------------------------------------------------------------
__global__ __launch_bounds__(256, 2) void gemm_qkv(
    const unsigned short* __restrict__ A16, const unsigned short* __restrict__ BTh,
    const float* __restrict__ bias, unsigned short* __restrict__ Cout,
    int K, int Nn) {
  __shared__ __align__(16) unsigned short sA[2 * 128 * 32];
  __shared__ __align__(16) unsigned short sB[2 * 256 * 32];

  const int tid = threadIdx.x;
  const int lane = tid & 63;
  const int wave = tid >> 6;
  const int wr = wave >> 1, wc = wave & 1;

  const int gx = gridDim.x;
  const int nwg = gx * gridDim.y;
  int bid = blockIdx.y * gx + blockIdx.x;
  bid = (bid & 7) * (nwg >> 3) + (bid >> 3);
  const int bm = (bid / gx) * 128;
  const int bn = (bid % gx) * 256;

  size_t aoff[2];
  int ldsA[2];
#pragma unroll
  for (int c = 0; c < 2; c++) {
    const int chunk = wave + 4 * c;
    const int e = chunk * 512 + lane * 8;
    const int r = e >> 5;
    const int kpos = (e >> 3) & 3;
    const int ksrc = kpos ^ ((r >> 1) & 3);
    aoff[c] = (size_t)(bm + r) * K + ksrc * 8;
    ldsA[c] = chunk * 512;
  }
  size_t boff[4];
  int ldsB[4];
#pragma unroll
  for (int c = 0; c < 4; c++) {
    const int chunk = wave + 4 * c;
    const int e = chunk * 512 + lane * 8;
    const int r = e >> 5;                   // 0..255
    const int kpos = (e >> 3) & 3;
    const int ksrc = kpos ^ ((r >> 1) & 3);
    boff[c] = (size_t)(bn + r) * K + ksrc * 8;
    ldsB[c] = chunk * 512;
  }

  const int fr = lane & 15;
  const int fkg = lane >> 4;

  int aroff[4], broff[8];
#pragma unroll
  for (int m = 0; m < 4; m++) {
    const int ra = wr * 64 + m * 16 + fr;
    aroff[m] = ra * 32 + ((fkg ^ ((ra >> 1) & 3)) << 3);
  }
#pragma unroll
  for (int n = 0; n < 8; n++) {
    const int rb = wc * 128 + n * 16 + fr;
    broff[n] = rb * 32 + ((fkg ^ ((rb >> 1) & 3)) << 3);
  }

  f32x4 acc[4][8] = {};

  const int NT = K >> 5;
#pragma unroll
  for (int c = 0; c < 2; c++) load_lds16(A16 + aoff[c], sA + ldsA[c]);
#pragma unroll
  for (int c = 0; c < 4; c++) load_lds16(BTh + boff[c], sB + ldsB[c]);
  __syncthreads();

  int cur = 0;
  for (int t = 0; t < NT; t++) {
    const int boA = cur * (128 * 32);
    const int boB = cur * (256 * 32);
    const int nxA = (cur ^ 1) * (128 * 32);
    const int nxB = (cur ^ 1) * (256 * 32);
    if (t + 1 < NT) {
      const int k0 = (t + 1) << 5;
#pragma unroll
      for (int c = 0; c < 2; c++) load_lds16(A16 + aoff[c] + k0, sA + nxA + ldsA[c]);
#pragma unroll
      for (int c = 0; c < 4; c++) load_lds16(BTh + boff[c] + k0, sB + nxB + ldsB[c]);
    }
    f16x8 a[4], bh[8];
#pragma unroll
    for (int m = 0; m < 4; m++) a[m] = *(const f16x8*)(sA + boA + aroff[m]);
#pragma unroll
    for (int n = 0; n < 8; n++) bh[n] = *(const f16x8*)(sB + boB + broff[n]);
    __builtin_amdgcn_s_setprio(1);
#pragma unroll
    for (int m = 0; m < 4; m++)
#pragma unroll
      for (int n = 0; n < 8; n++)
        acc[m][n] = __builtin_amdgcn_mfma_f32_16x16x32_f16(a[m], bh[n], acc[m][n], 0, 0, 0);
    __builtin_amdgcn_s_setprio(0);
    __syncthreads();
    cur ^= 1;
  }

#pragma unroll
  for (int m = 0; m < 4; m++) {
    const int row = bm + wr * 64 + m * 16 + fkg * 4;
#pragma unroll
    for (int n = 0; n < 8; n++) {
      const int col = bn + wc * 128 + n * 16 + fr;
      const float bsv = bias[col];
#pragma unroll
      for (int j = 0; j < 4; j++) {
        const float v = acc[m][n][j] + bsv;
        Cout[(size_t)(row + j) * Nn + col] =
            __builtin_bit_cast(unsigned short, (_Float16)v);
      }
    }
  }
}

// ---------------------------------------------------------------------------
// O-projection GEMM (proven 128x128, fp32 out), 2-phase dbuf, 4 blocks/CU.
// ---------------------------------------------------------------------------
__global__ __launch_bounds__(256, 4) void gemm_o(
    const unsigned short* __restrict__ A16, const unsigned short* __restrict__ BTh,
    const float* __restrict__ bias, float* __restrict__ Cout, int K, int Nn) {
  __shared__ __align__(16) unsigned short sA[2 * 128 * 32];
  __shared__ __align__(16) unsigned short sB[2 * 128 * 32];

  const int tid = threadIdx.x;
  const int lane = tid & 63;
  const int wave = tid >> 6;
  const int wr = wave >> 1, wc = wave & 1;

  const int gx = gridDim.x;
  const int nwg = gx * gridDim.y;
  int bid = blockIdx.y * gx + blockIdx.x;
  bid = (bid & 7) * (nwg >> 3) + (bid >> 3);
  const int bm = (bid / gx) * 128;
  const int bn = (bid % gx) * 128;

  size_t aoff[2], boff[2];
  int ldsoff[2];
#pragma unroll
  for (int c = 0; c < 2; c++) {
    const int chunk = wave + 4 * c;
    const int e = chunk * 512 + lane * 8;
    const int r = e >> 5;
    const int kpos = (e >> 3) & 3;
    const int ksrc = kpos ^ ((r >> 1) & 3);
    aoff[c] = (size_t)(bm + r) * K + ksrc * 8;
    boff[c] = (size_t)(bn + r) * K + ksrc * 8;
    ldsoff[c] = chunk * 512;
  }

  const int fr = lane & 15;
  const int fkg = lane >> 4;

  int aroff[4], broff[4];
#pragma unroll
  for (int m = 0; m < 4; m++) {
    const int ra = wr * 64 + m * 16 + fr;
    aroff[m] = ra * 32 + ((fkg ^ ((ra >> 1) & 3)) << 3);
    const int rb = wc * 64 + m * 16 + fr;
    broff[m] = rb * 32 + ((fkg ^ ((rb >> 1) & 3)) << 3);
  }

  f32x4 acc[4][4] = {};

  const int NT = K >> 5;
#pragma unroll
  for (int c = 0; c < 2; c++) {
    load_lds16(A16 + aoff[c], sA + ldsoff[c]);
    load_lds16(BTh + boff[c], sB + ldsoff[c]);
  }
  __syncthreads();

  int cur = 0;
  for (int t = 0; t < NT; t++) {
    const int bo_ = cur * (128 * 32);
    const int nx_ = (cur ^ 1) * (128 * 32);
    if (t + 1 < NT) {
      const int k0 = (t + 1) << 5;
#pragma unroll
      for (int c = 0; c < 2; c++) {
        load_lds16(A16 + aoff[c] + k0, sA + nx_ + ldsoff[c]);
        load_lds16(BTh + boff[c] + k0, sB + nx_ + ldsoff[c]);
      }
    }
    f16x8 a[4], bh[4];
#pragma unroll
    for (int m = 0; m < 4; m++) a[m] = *(const f16x8*)(sA + bo_ + aroff[m]);
#pragma unroll
    for (int n = 0; n < 4; n++) bh[n] = *(const f16x8*)(sB + bo_ + broff[n]);
    __builtin_amdgcn_s_setprio(1);
#pragma unroll
    for (int m = 0; m < 4; m++)
#pragma unroll
      for (int n = 0; n < 4; n++)
        acc[m][n] = __builtin_amdgcn_mfma_f32_16x16x32_f16(a[m], bh[n], acc[m][n], 0, 0, 0);
    __builtin_amdgcn_s_setprio(0);
    __syncthreads();
    cur ^= 1;
  }

#pragma unroll
  for (int m = 0; m < 4; m++) {
    const int row = bm + wr * 64 + m * 16 + fkg * 4;
#pragma unroll
    for (int n = 0; n < 4; n++) {
      const int col = bn + wc * 64 + n * 16 + fr;
      const float bsv = bias[col];
#pragma unroll
      for (int j = 0; j < 4; j++)
        Cout[(size_t)(row + j) * Nn + col] = acc[m][n][j] + bsv;
    }
  }
}

// ---------------------------------------------------------------------------
// Vsum two-stage over fp16 v.
// ---------------------------------------------------------------------------
__global__ __launch_bounds__(256) void vsum_part(const unsigned short* __restrict__ v,
                                                 float* __restrict__ part) {
  const int b = blockIdx.x >> 4;
  const int chunk = blockIdx.x & 15;
  const int d4 = threadIdx.x * 4;
  const unsigned short* p =
      v + (size_t)b * N * LDQKV + (size_t)chunk * 64 * LDQKV + d4;
  float4 s = {0.f, 0.f, 0.f, 0.f};
#pragma unroll 8
  for (int n = 0; n < 64; n++) {
    us4 t = *(const us4*)(p + (size_t)n * LDQKV);
    s.x += h2f(t[0]); s.y += h2f(t[1]); s.z += h2f(t[2]); s.w += h2f(t[3]);
  }
  *(float4*)(part + (size_t)blockIdx.x * 1024 + d4) = s;
}

__global__ __launch_bounds__(256) void vsum_comb(const float* __restrict__ part,
                                                 float* __restrict__ vsum) {
  const int i = blockIdx.x * 256 + threadIdx.x;  // b*1024 + d
  const int b = i >> 10, d = i & 1023;
  float s = 0.f;
#pragma unroll
  for (int c = 0; c < 16; c++) s += part[(size_t)(b * 16 + c) * 1024 + d];
  vsum[i] = s;
}

// ---------------------------------------------------------------------------
// pass1 (FUSED attn-row write): 4 heads per block, one wave per head.
// Gather-dot 32 keys, closed-form softmax, fp16 O plane; each wave stages
// its 4 KB attn row in LDS and NT-stores it — rows >= SROWS only (rows <
// SROWS still hold scratch; their p/base go to ws, written by attn_fill_rem).
// `fused` is BLOCK-uniform (boundary b=0,h=12; h spans hg*4..hg*4+3), so the
// __syncthreads() in the fused path are safe. The barriers are REQUIRED:
// mixed f32x4/float LDS accesses — TBAA lets the compiler forward the fill
// past the scatter without them (round-14 failure).
// ---------------------------------------------------------------------------
__global__ __launch_bounds__(256) void attn_pass1(
    const unsigned short* __restrict__ qkv16, const float* __restrict__ vsum,
    const int* __restrict__ graph, float* __restrict__ pbuf,
    float* __restrict__ basebuf, unsigned short* __restrict__ O16,
    float* __restrict__ attn) {
  const int blk = blockIdx.x;         // b*4096 + hg*1024 + n
  const int n = blk & (N - 1);
  const int hg = (blk >> 10) & 3;
  const int b = blk >> 12;
  const int wave = threadIdx.x >> 6;
  const int lane = threadIdx.x & 63;
  const int h = hg * 4 + wave;
  const int bid = (b * H + h) * N + n;  // attn row id

  __shared__ float q_sh[4][DEPTH];
  __shared__ int g_sh[W];
  __shared__ float p_sh[4][W];
  __shared__ float rowbuf[4][N];      // 16 KB: per-wave attn row staging

  const unsigned short* qrow = qkv16 + (size_t)(b * N + n) * LDQKV + h * DEPTH;
  q_sh[wave][lane] = h2f(qrow[lane]);
  if (threadIdx.x < W) g_sh[threadIdx.x] = graph[n * W + threadIdx.x];
  __syncthreads();

  const int w = lane >> 1;
  const int half = lane & 1;
  const unsigned short* krow =
      qkv16 + 1024 + (size_t)(b * N + g_sh[w]) * LDQKV + h * DEPTH + half * 32;
  float acc = 0.f;
#pragma unroll
  for (int j8 = 0; j8 < 4; j8++) {
    us8 kv = *(const us8*)(krow + j8 * 8);
    const float* qh = &q_sh[wave][half * 32 + j8 * 8];
#pragma unroll
    for (int e = 0; e < 8; e++) acc += h2f(kv[e]) * qh[e];
  }
  acc += __shfl_xor(acc, 1);
  const float dot = acc * 0.125f;

  float m = dot;
#pragma unroll
  for (int off = 2; off < 64; off <<= 1) m = fmaxf(m, __shfl_xor(m, off));
  m = fmaxf(m, 0.f);

  const float e = expf(dot - m);
  float s = e;
#pragma unroll
  for (int off = 1; off < 64; off <<= 1) s += __shfl_xor(s, off);
  s *= 0.5f;

  const float em = expf(-m);
  const float Z = (float)(N - W) * em + s;
  const float inv = 1.f / Z;
  const float base = em * inv;   // wave-uniform
  const float pw = e * inv;

  if (half == 0) p_sh[wave][w] = pw;
  __syncthreads();

  const bool fused = (bid >= SROWS);  // block-uniform (see header comment)
  if (!fused) {
    if (half == 0) pbuf[(size_t)bid * W + w] = pw;
    if (lane == 0) basebuf[bid] = base;
  }

  const unsigned short* vbase = qkv16 + 2048;
  const int col = h * DEPTH + lane;
  float ov = base * vsum[b * D + col];
#pragma unroll 4
  for (int ww = 0; ww < W; ww++) {
    ov += (p_sh[wave][ww] - base) *
          h2f(vbase[(size_t)(b * N + g_sh[ww]) * LDQKV + col]);
  }
  _Float16 hh = (_Float16)ov;
  O16[(size_t)(b * N + n) * D + col] = __builtin_bit_cast(unsigned short, hh);

  // fused attn-row write (rows >= SROWS only; block-uniform branch)
  if (fused) {
    f32x4* rw = (f32x4*)rowbuf[wave];
    f32x4 b4v = {base, base, base, base};
#pragma unroll
    for (int i = 0; i < 4; i++) rw[lane + 64 * i] = b4v;
    __syncthreads();  // order fill before scatter (mixed-type LDS, TBAA)
    if (half == 0) rowbuf[wave][g_sh[w]] = pw;
    __syncthreads();  // order scatter before vector read
    f32x4* dst = (f32x4*)(attn + (size_t)bid * N);
#pragma unroll
    for (int i = 0; i < 4; i++)
      __builtin_nontemporal_store(rw[lane + 64 * i], dst + lane + 64 * i);
  }
}

// ---------------------------------------------------------------------------
// Remainder fill: rows [0, SROWS) = b=0, h=0..11. 2 rows per block
// (h, h+6 share the graph row). Runs after gemm_o has consumed O16.
// ---------------------------------------------------------------------------
__global__ __launch_bounds__(256) void attn_fill_rem(
    const float* __restrict__ pbuf, const float* __restrict__ basebuf,
    const int* __restrict__ graph, float* __restrict__ attn) {
  const int blk = blockIdx.x;          // hh*1024 + n, hh in 0..5
  const int n = blk & (N - 1);
  const int hh = blk >> 10;
  const int t = threadIdx.x;

  __shared__ float row[2][N];
  __shared__ int g_sh[W];

  const int bid0 = hh * N + n;          // h = hh
  const int bid1 = (hh + 6) * N + n;    // h = hh+6

  if (t < W) g_sh[t] = graph[n * W + t];
  const float base0 = basebuf[bid0];
  const float base1 = basebuf[bid1];
  f32x4* row40 = (f32x4*)row[0];
  f32x4* row41 = (f32x4*)row[1];
  row40[t] = (f32x4){base0, base0, base0, base0};
  row41[t] = (f32x4){base1, base1, base1, base1};
  __syncthreads();
  if (t < 2 * W) {
    const int r = t >> 5;
    const int w = t & 31;
    const int bidr = r == 0 ? bid0 : bid1;
    row[r][g_sh[w]] = pbuf[(size_t)bidr * W + w];
  }
  __syncthreads();
  __builtin_nontemporal_store(row40[t], (f32x4*)(attn + (size_t)bid0 * N) + t);
  __builtin_nontemporal_store(row41[t], (f32x4*)(attn + (size_t)bid1 * N) + t);
}

// ---------------------------------------------------------------------------
extern "C" void kernel_launch(void* const* d_in, const int* in_sizes, int n_in,
                              void* d_out, int out_size, void* d_ws, size_t ws_size,
                              hipStream_t stream) {
  const float* hidden = (const float*)d_in[0];
  const float* wq = (const float*)d_in[1];
  const float* bq = (const float*)d_in[2];
  const float* wk = (const float*)d_in[3];
  const float* bk = (const float*)d_in[4];
  const float* wv = (const float*)d_in[5];
  const float* bv = (const float*)d_in[6];
  const float* wo = (const float*)d_in[7];
  const float* bo = (const float*)d_in[8];
  const int* graph = (const int*)d_in[9];

  float* out0 = (float*)d_out;                 // (B,N,D) final output
  float* attnp = out0 + (size_t)B * N * D;     // (B,H,N,N)

  // scratch packed into attn rows [0, SROWS) — exactly 12M floats:
  const size_t M1 = (size_t)1024 * 1024;
  unsigned short* qkv16 = (unsigned short*)attnp;              // [0, 6M)
  unsigned short* A16 = (unsigned short*)(attnp + 6 * M1);     // [6M, 8M)
  unsigned short* BTh = (unsigned short*)(attnp + 8 * M1);     // [8M, 9.5M)
  unsigned short* WoTh = (unsigned short*)(attnp + 9 * M1 + 524288); // [9.5M, 10M)
  unsigned short* O16 = (unsigned short*)(attnp + 10 * M1);    // [10M, 12M)

  // ws: pbuf/basebuf/vsumb; biasq+vpart OVERLAY pbuf (dead before pbuf use)
  float* pbuf = (float*)d_ws;                        // 2M floats
  float* basebuf = pbuf + (size_t)B * H * N * W;     // 65536
  float* vsumb = basebuf + (size_t)B * H * N;        // 4096
  float* biasq = pbuf;                               // 3072   (pre-pass1 only)
  float* vpart = pbuf + 4096;                        // 65536  (pre-pass1 only)

  prep_all<<<3084, 256, 0, stream>>>(hidden, wq, wk, wv, wo, bq, bk, bv,
                                     A16, BTh, WoTh, biasq);

  gemm_qkv<<<dim3(12, 32), 256, 0, stream>>>(A16, BTh, biasq, qkv16,
                                             1024, 3072);

  vsum_part<<<64, 256, 0, stream>>>(qkv16 + 2048, vpart);
  vsum_comb<<<16, 256, 0, stream>>>(vpart, vsumb);

  attn_pass1<<<B * 4 * N, 256, 0, stream>>>(qkv16, vsumb, graph, pbuf, basebuf,
                                            O16, attnp);

  gemm_o<<<dim3(8, 32), 256, 0, stream>>>(O16, WoTh, bo, out0, 1024, 1024);

  attn_fill_rem<<<SROWS / 2, 256, 0, stream>>>(pbuf, basebuf, graph, attnp);
}

// Round 16
// 148.816 us; speedup vs baseline: 1.4211x; 1.0376x over previous
//
#include <hip/hip_runtime.h>
#include <hip/hip_bf16.h>

constexpr int B = 4;
constexpr int N = 1024;
constexpr int D = 1024;
constexpr int H = 16;
constexpr int DEPTH = 64;
constexpr int W = 32;
constexpr int LDQKV = 3072;   // fused q|k|v row stride (f16 elements)
constexpr int SROWS = 10240;  // attn rows [0,SROWS) hold scratch during pass1

typedef _Float16 f16x8 __attribute__((ext_vector_type(8)));
typedef float f32x4 __attribute__((ext_vector_type(4)));
typedef unsigned short us8 __attribute__((ext_vector_type(8)));
typedef unsigned short us4 __attribute__((ext_vector_type(4)));

__device__ __forceinline__ float h2f(unsigned short u) {
  return (float)__builtin_bit_cast(_Float16, u);
}

// ---------------------------------------------------------------------------
// async global->LDS, 16B per lane (wave-uniform LDS base, HW adds lane*16)
// ---------------------------------------------------------------------------
__device__ __forceinline__ void load_lds16(const void* g, void* l) {
  unsigned int lo = (unsigned int)(unsigned long long)l;
  __builtin_amdgcn_global_load_lds(
      (const __attribute__((address_space(1))) unsigned int*)g,
      (__attribute__((address_space(3))) unsigned int*)lo, 16, 0, 0);
}

// ---------------------------------------------------------------------------
// Fused prep: grid sections
//   [0, 2048)       cvt_half: hidden fp32 -> A16 fp16
//   [2048, 3072)    txp_cvt:  wq/wk/wv/wo -> transposed fp16 (hi only)
//   [3072, 3084)    bias_concat
// ---------------------------------------------------------------------------
__global__ __launch_bounds__(256) void prep_all(
    const float* __restrict__ hidden, const float* __restrict__ wq,
    const float* __restrict__ wk, const float* __restrict__ wv,
    const float* __restrict__ wo, const float* __restrict__ bq,
    const float* __restrict__ bk, const float* __restrict__ bv,
    unsigned short* __restrict__ A16, unsigned short* __restrict__ BTh,
    unsigned short* __restrict__ WoTh, float* __restrict__ biasq) {
  __shared__ float sf[64][65];
  const int t = threadIdx.x;
  int blk = blockIdx.x;

  if (blk < 2048) {  // ---- cvt_half section ----
    const size_t i = ((size_t)blk * 256 + t) * 8;
    float4 a = *(const float4*)(hidden + i);
    float4 b = *(const float4*)(hidden + i + 4);
    float xs[8] = {a.x, a.y, a.z, a.w, b.x, b.y, b.z, b.w};
    us8 hv;
#pragma unroll
    for (int j = 0; j < 8; j++)
      hv[j] = __builtin_bit_cast(unsigned short, (_Float16)xs[j]);
    *(us8*)(A16 + i) = hv;
    return;
  }
  blk -= 2048;
  if (blk < 1024) {  // ---- txp_cvt sections (4 weights x 256 blocks) ----
    const int which = blk >> 8;       // 0=wq 1=wk 2=wv 3=wo
    const int sub = blk & 255;
    const float* w = which == 0 ? wq : which == 1 ? wk : which == 2 ? wv : wo;
    unsigned short* oh = which < 3 ? BTh : WoTh;
    const int rowOff = which < 3 ? which * 1024 : 0;

    const int tn = (sub & 15) * 64;   // src col block
    const int tk = (sub >> 4) * 64;   // src row block
#pragma unroll
    for (int i = 0; i < 4; i++) {
      int f = i * 256 + t;
      int r = f >> 4, c4 = (f & 15) * 4;
      float4 v = *(const float4*)(w + (size_t)(tk + r) * 1024 + tn + c4);
      sf[r][c4 + 0] = v.x; sf[r][c4 + 1] = v.y;
      sf[r][c4 + 2] = v.z; sf[r][c4 + 3] = v.w;
    }
    __syncthreads();
    const int n = t >> 2;             // out row (src col)
    const int kc = (t & 3) * 16;      // k chunk
    us8 hv[2];
#pragma unroll
    for (int half = 0; half < 2; half++) {
#pragma unroll
      for (int j = 0; j < 8; j++) {
        float x = sf[kc + half * 8 + j][n];
        hv[half][j] = __builtin_bit_cast(unsigned short, (_Float16)x);
      }
    }
    size_t dst = (size_t)(rowOff + tn + n) * 1024 + tk + kc;
    *(us8*)(oh + dst) = hv[0];
    *(us8*)(oh + dst + 8) = hv[1];
    return;
  }
  blk -= 1024;  // ---- bias_concat section (12 blocks) ----
  int i = blk * 256 + t;
  biasq[i] = i < 1024 ? bq[i] : (i < 2048 ? bk[i - 1024] : bv[i - 2048]);
}

// ---------------------------------------------------------------------------
// QKV GEMM: 128x256 tile, wave = 64x128 (acc 4x8). BK=32, 4 waves,
// 2-phase dbuf (48 KB LDS), f16 out. Granule swizzle k'=k^((r>>1)&3) on
// global source + ds_read. T1 XCD swizzle; T5 setprio.
// NEW: V-column blocks (bn >= 2048, block-uniform) also emit per-tile
// column-sum partials vpart[tileRow][d] (pre-bias) for the Vsum — kills the
// separate 8 MB strided vsum_part pass. Deterministic: unique cell per block.
// ---------------------------------------------------------------------------
__global__ __launch_bounds__(256, 2) void gemm_qkv(
    const unsigned short* __restrict__ A16, const unsigned short* __restrict__ BTh,
    const float* __restrict__ bias, unsigned short* __restrict__ Cout,
    float* __restrict__ vpart, int K, int Nn) {
  __shared__ __align__(16) unsigned short sA[2 * 128 * 32];
  __shared__ __align__(16) unsigned short sB[2 * 256 * 32];
  __shared__ float vred[2][2][8][16];  // [wr][wc][n][fr], 2 KB

  const int tid = threadIdx.x;
  const int lane = tid & 63;
  const int wave = tid >> 6;
  const int wr = wave >> 1, wc = wave & 1;

  const int gx = gridDim.x;
  const int nwg = gx * gridDim.y;
  int bid = blockIdx.y * gx + blockIdx.x;
  bid = (bid & 7) * (nwg >> 3) + (bid >> 3);
  const int bm = (bid / gx) * 128;
  const int bn = (bid % gx) * 256;

  size_t aoff[2];
  int ldsA[2];
#pragma unroll
  for (int c = 0; c < 2; c++) {
    const int chunk = wave + 4 * c;
    const int e = chunk * 512 + lane * 8;
    const int r = e >> 5;
    const int kpos = (e >> 3) & 3;
    const int ksrc = kpos ^ ((r >> 1) & 3);
    aoff[c] = (size_t)(bm + r) * K + ksrc * 8;
    ldsA[c] = chunk * 512;
  }
  size_t boff[4];
  int ldsB[4];
#pragma unroll
  for (int c = 0; c < 4; c++) {
    const int chunk = wave + 4 * c;
    const int e = chunk * 512 + lane * 8;
    const int r = e >> 5;                   // 0..255
    const int kpos = (e >> 3) & 3;
    const int ksrc = kpos ^ ((r >> 1) & 3);
    boff[c] = (size_t)(bn + r) * K + ksrc * 8;
    ldsB[c] = chunk * 512;
  }

  const int fr = lane & 15;
  const int fkg = lane >> 4;

  int aroff[4], broff[8];
#pragma unroll
  for (int m = 0; m < 4; m++) {
    const int ra = wr * 64 + m * 16 + fr;
    aroff[m] = ra * 32 + ((fkg ^ ((ra >> 1) & 3)) << 3);
  }
#pragma unroll
  for (int n = 0; n < 8; n++) {
    const int rb = wc * 128 + n * 16 + fr;
    broff[n] = rb * 32 + ((fkg ^ ((rb >> 1) & 3)) << 3);
  }

  f32x4 acc[4][8] = {};

  const int NT = K >> 5;
#pragma unroll
  for (int c = 0; c < 2; c++) load_lds16(A16 + aoff[c], sA + ldsA[c]);
#pragma unroll
  for (int c = 0; c < 4; c++) load_lds16(BTh + boff[c], sB + ldsB[c]);
  __syncthreads();

  int cur = 0;
  for (int t = 0; t < NT; t++) {
    const int boA = cur * (128 * 32);
    const int boB = cur * (256 * 32);
    const int nxA = (cur ^ 1) * (128 * 32);
    const int nxB = (cur ^ 1) * (256 * 32);
    if (t + 1 < NT) {
      const int k0 = (t + 1) << 5;
#pragma unroll
      for (int c = 0; c < 2; c++) load_lds16(A16 + aoff[c] + k0, sA + nxA + ldsA[c]);
#pragma unroll
      for (int c = 0; c < 4; c++) load_lds16(BTh + boff[c] + k0, sB + nxB + ldsB[c]);
    }
    f16x8 a[4], bh[8];
#pragma unroll
    for (int m = 0; m < 4; m++) a[m] = *(const f16x8*)(sA + boA + aroff[m]);
#pragma unroll
    for (int n = 0; n < 8; n++) bh[n] = *(const f16x8*)(sB + boB + broff[n]);
    __builtin_amdgcn_s_setprio(1);
#pragma unroll
    for (int m = 0; m < 4; m++)
#pragma unroll
      for (int n = 0; n < 8; n++)
        acc[m][n] = __builtin_amdgcn_mfma_f32_16x16x32_f16(a[m], bh[n], acc[m][n], 0, 0, 0);
    __builtin_amdgcn_s_setprio(0);
    __syncthreads();
    cur ^= 1;
  }

  // epilogue: C/D layout col=lane&15, row=(lane>>4)*4+j; f16 out
#pragma unroll
  for (int m = 0; m < 4; m++) {
    const int row = bm + wr * 64 + m * 16 + fkg * 4;
#pragma unroll
    for (int n = 0; n < 8; n++) {
      const int col = bn + wc * 128 + n * 16 + fr;
      const float bsv = bias[col];
#pragma unroll
      for (int j = 0; j < 4; j++) {
        const float v = acc[m][n][j] + bsv;
        Cout[(size_t)(row + j) * Nn + col] =
            __builtin_bit_cast(unsigned short, (_Float16)v);
      }
    }
  }

  // V column-sum partials (block-uniform branch; barrier inside is safe)
  if (bn >= 2048) {
    float csum[8];
#pragma unroll
    for (int n = 0; n < 8; n++) {
      float s = 0.f;
#pragma unroll
      for (int m = 0; m < 4; m++)
#pragma unroll
        for (int j = 0; j < 4; j++) s += acc[m][n][j];
      s += __shfl_xor(s, 16);   // sum across fkg bit0
      s += __shfl_xor(s, 32);   // sum across fkg bit1
      csum[n] = s;              // this wave's 64-row column sum
    }
    if (fkg == 0) {
#pragma unroll
      for (int n = 0; n < 8; n++) vred[wr][wc][n][fr] = csum[n];
    }
    __syncthreads();
    if (wr == 0 && fkg == 0) {
#pragma unroll
      for (int n = 0; n < 8; n++) {
        const int d = bn - 2048 + wc * 128 + n * 16 + fr;
        vpart[(size_t)(bm >> 7) * 1024 + d] = csum[n] + vred[1][wc][n][fr];
      }
    }
  }
}

// ---------------------------------------------------------------------------
// O-projection GEMM (proven 128x128, fp32 out), 2-phase dbuf, 4 blocks/CU.
// ---------------------------------------------------------------------------
__global__ __launch_bounds__(256, 4) void gemm_o(
    const unsigned short* __restrict__ A16, const unsigned short* __restrict__ BTh,
    const float* __restrict__ bias, float* __restrict__ Cout, int K, int Nn) {
  __shared__ __align__(16) unsigned short sA[2 * 128 * 32];
  __shared__ __align__(16) unsigned short sB[2 * 128 * 32];

  const int tid = threadIdx.x;
  const int lane = tid & 63;
  const int wave = tid >> 6;
  const int wr = wave >> 1, wc = wave & 1;

  const int gx = gridDim.x;
  const int nwg = gx * gridDim.y;
  int bid = blockIdx.y * gx + blockIdx.x;
  bid = (bid & 7) * (nwg >> 3) + (bid >> 3);
  const int bm = (bid / gx) * 128;
  const int bn = (bid % gx) * 128;

  size_t aoff[2], boff[2];
  int ldsoff[2];
#pragma unroll
  for (int c = 0; c < 2; c++) {
    const int chunk = wave + 4 * c;
    const int e = chunk * 512 + lane * 8;
    const int r = e >> 5;
    const int kpos = (e >> 3) & 3;
    const int ksrc = kpos ^ ((r >> 1) & 3);
    aoff[c] = (size_t)(bm + r) * K + ksrc * 8;
    boff[c] = (size_t)(bn + r) * K + ksrc * 8;
    ldsoff[c] = chunk * 512;
  }

  const int fr = lane & 15;
  const int fkg = lane >> 4;

  int aroff[4], broff[4];
#pragma unroll
  for (int m = 0; m < 4; m++) {
    const int ra = wr * 64 + m * 16 + fr;
    aroff[m] = ra * 32 + ((fkg ^ ((ra >> 1) & 3)) << 3);
    const int rb = wc * 64 + m * 16 + fr;
    broff[m] = rb * 32 + ((fkg ^ ((rb >> 1) & 3)) << 3);
  }

  f32x4 acc[4][4] = {};

  const int NT = K >> 5;
#pragma unroll
  for (int c = 0; c < 2; c++) {
    load_lds16(A16 + aoff[c], sA + ldsoff[c]);
    load_lds16(BTh + boff[c], sB + ldsoff[c]);
  }
  __syncthreads();

  int cur = 0;
  for (int t = 0; t < NT; t++) {
    const int bo_ = cur * (128 * 32);
    const int nx_ = (cur ^ 1) * (128 * 32);
    if (t + 1 < NT) {
      const int k0 = (t + 1) << 5;
#pragma unroll
      for (int c = 0; c < 2; c++) {
        load_lds16(A16 + aoff[c] + k0, sA + nx_ + ldsoff[c]);
        load_lds16(BTh + boff[c] + k0, sB + nx_ + ldsoff[c]);
      }
    }
    f16x8 a[4], bh[4];
#pragma unroll
    for (int m = 0; m < 4; m++) a[m] = *(const f16x8*)(sA + bo_ + aroff[m]);
#pragma unroll
    for (int n = 0; n < 4; n++) bh[n] = *(const f16x8*)(sB + bo_ + broff[n]);
    __builtin_amdgcn_s_setprio(1);
#pragma unroll
    for (int m = 0; m < 4; m++)
#pragma unroll
      for (int n = 0; n < 4; n++)
        acc[m][n] = __builtin_amdgcn_mfma_f32_16x16x32_f16(a[m], bh[n], acc[m][n], 0, 0, 0);
    __builtin_amdgcn_s_setprio(0);
    __syncthreads();
    cur ^= 1;
  }

#pragma unroll
  for (int m = 0; m < 4; m++) {
    const int row = bm + wr * 64 + m * 16 + fkg * 4;
#pragma unroll
    for (int n = 0; n < 4; n++) {
      const int col = bn + wc * 64 + n * 16 + fr;
      const float bsv = bias[col];
#pragma unroll
      for (int j = 0; j < 4; j++)
        Cout[(size_t)(row + j) * Nn + col] = acc[m][n][j] + bsv;
    }
  }
}

// ---------------------------------------------------------------------------
// Vsum combine: vsum[b,d] = sum_{c=0..7} vpart[b*8+c][d] + 1024*bv[d]
// (partials are pre-bias; each of the 1024 rows contributes bv once)
// ---------------------------------------------------------------------------
__global__ __launch_bounds__(256) void vsum_comb(const float* __restrict__ vpart,
                                                 const float* __restrict__ biasq,
                                                 float* __restrict__ vsum) {
  const int i = blockIdx.x * 256 + threadIdx.x;  // b*1024 + d
  const int b = i >> 10, d = i & 1023;
  float s = 1024.0f * biasq[2048 + d];
#pragma unroll
  for (int c = 0; c < 8; c++) s += vpart[(size_t)(b * 8 + c) * 1024 + d];
  vsum[i] = s;
}

// ---------------------------------------------------------------------------
// pass1 (FUSED attn-row write): 4 heads per block, one wave per head.
// Gather-dot 32 keys, closed-form softmax, fp16 O plane; each wave stages
// its 4 KB attn row in LDS and NT-stores it — rows >= SROWS only.
// SROWS=10240 is NOT block-uniform (h=10 boundary inside a 4-head block),
// so the rowbuf fill and BOTH barriers run unconditionally; only the
// barrier-free pbuf-write / scatter / NT-store are conditioned (wave-uniform).
// Barriers are REQUIRED between mixed f32x4/float LDS accesses (TBAA —
// round-14 failure).
// ---------------------------------------------------------------------------
__global__ __launch_bounds__(256) void attn_pass1(
    const unsigned short* __restrict__ qkv16, const float* __restrict__ vsum,
    const int* __restrict__ graph, float* __restrict__ pbuf,
    float* __restrict__ basebuf, unsigned short* __restrict__ O16,
    float* __restrict__ attn) {
  const int blk = blockIdx.x;         // b*4096 + hg*1024 + n
  const int n = blk & (N - 1);
  const int hg = (blk >> 10) & 3;
  const int b = blk >> 12;
  const int wave = threadIdx.x >> 6;
  const int lane = threadIdx.x & 63;
  const int h = hg * 4 + wave;
  const int bid = (b * H + h) * N + n;  // attn row id

  __shared__ float q_sh[4][DEPTH];
  __shared__ int g_sh[W];
  __shared__ float p_sh[4][W];
  __shared__ float rowbuf[4][N];      // 16 KB: per-wave attn row staging

  const unsigned short* qrow = qkv16 + (size_t)(b * N + n) * LDQKV + h * DEPTH;
  q_sh[wave][lane] = h2f(qrow[lane]);
  if (threadIdx.x < W) g_sh[threadIdx.x] = graph[n * W + threadIdx.x];
  __syncthreads();

  const int w = lane >> 1;
  const int half = lane & 1;
  const unsigned short* krow =
      qkv16 + 1024 + (size_t)(b * N + g_sh[w]) * LDQKV + h * DEPTH + half * 32;
  float acc = 0.f;
#pragma unroll
  for (int j8 = 0; j8 < 4; j8++) {
    us8 kv = *(const us8*)(krow + j8 * 8);
    const float* qh = &q_sh[wave][half * 32 + j8 * 8];
#pragma unroll
    for (int e = 0; e < 8; e++) acc += h2f(kv[e]) * qh[e];
  }
  acc += __shfl_xor(acc, 1);
  const float dot = acc * 0.125f;

  float m = dot;
#pragma unroll
  for (int off = 2; off < 64; off <<= 1) m = fmaxf(m, __shfl_xor(m, off));
  m = fmaxf(m, 0.f);

  const float e = expf(dot - m);
  float s = e;
#pragma unroll
  for (int off = 1; off < 64; off <<= 1) s += __shfl_xor(s, off);
  s *= 0.5f;

  const float em = expf(-m);
  const float Z = (float)(N - W) * em + s;
  const float inv = 1.f / Z;
  const float base = em * inv;   // wave-uniform
  const float pw = e * inv;

  if (half == 0) p_sh[wave][w] = pw;
  __syncthreads();

  const bool fused = (bid >= SROWS);  // wave-uniform
  if (!fused) {
    if (half == 0) pbuf[(size_t)bid * W + w] = pw;
    if (lane == 0) basebuf[bid] = base;
  }

  const unsigned short* vbase = qkv16 + 2048;
  const int col = h * DEPTH + lane;
  float ov = base * vsum[b * D + col];
#pragma unroll 4
  for (int ww = 0; ww < W; ww++) {
    ov += (p_sh[wave][ww] - base) *
          h2f(vbase[(size_t)(b * N + g_sh[ww]) * LDQKV + col]);
  }
  _Float16 hh = (_Float16)ov;
  O16[(size_t)(b * N + n) * D + col] = __builtin_bit_cast(unsigned short, hh);

  // attn-row staging: fill + barriers UNCONDITIONAL (fused is not
  // block-uniform at the h=10 boundary); scatter/store are wave-uniform.
  f32x4* rw = (f32x4*)rowbuf[wave];
  f32x4 b4v = {base, base, base, base};
#pragma unroll
  for (int i = 0; i < 4; i++) rw[lane + 64 * i] = b4v;
  __syncthreads();  // order fill before scatter (mixed-type LDS, TBAA)
  if (fused && half == 0) rowbuf[wave][g_sh[w]] = pw;
  __syncthreads();  // order scatter before vector read
  if (fused) {
    f32x4* dst = (f32x4*)(attn + (size_t)bid * N);
#pragma unroll
    for (int i = 0; i < 4; i++)
      __builtin_nontemporal_store(rw[lane + 64 * i], dst + lane + 64 * i);
  }
}

// ---------------------------------------------------------------------------
// Remainder fill: rows [0, SROWS) = b=0, h=0..9. 2 rows per block
// (h, h+5 share the graph row). Runs after gemm_o has consumed O16.
// ---------------------------------------------------------------------------
__global__ __launch_bounds__(256) void attn_fill_rem(
    const float* __restrict__ pbuf, const float* __restrict__ basebuf,
    const int* __restrict__ graph, float* __restrict__ attn) {
  const int blk = blockIdx.x;          // hh*1024 + n, hh in 0..4
  const int n = blk & (N - 1);
  const int hh = blk >> 10;
  const int t = threadIdx.x;

  __shared__ float row[2][N];
  __shared__ int g_sh[W];

  const int bid0 = hh * N + n;          // h = hh
  const int bid1 = (hh + 5) * N + n;    // h = hh+5

  if (t < W) g_sh[t] = graph[n * W + t];
  const float base0 = basebuf[bid0];
  const float base1 = basebuf[bid1];
  f32x4* row40 = (f32x4*)row[0];
  f32x4* row41 = (f32x4*)row[1];
  row40[t] = (f32x4){base0, base0, base0, base0};
  row41[t] = (f32x4){base1, base1, base1, base1};
  __syncthreads();
  if (t < 2 * W) {
    const int r = t >> 5;
    const int w = t & 31;
    const int bidr = r == 0 ? bid0 : bid1;
    row[r][g_sh[w]] = pbuf[(size_t)bidr * W + w];
  }
  __syncthreads();
  __builtin_nontemporal_store(row40[t], (f32x4*)(attn + (size_t)bid0 * N) + t);
  __builtin_nontemporal_store(row41[t], (f32x4*)(attn + (size_t)bid1 * N) + t);
}

// ---------------------------------------------------------------------------
extern "C" void kernel_launch(void* const* d_in, const int* in_sizes, int n_in,
                              void* d_out, int out_size, void* d_ws, size_t ws_size,
                              hipStream_t stream) {
  const float* hidden = (const float*)d_in[0];
  const float* wq = (const float*)d_in[1];
  const float* bq = (const float*)d_in[2];
  const float* wk = (const float*)d_in[3];
  const float* bk = (const float*)d_in[4];
  const float* wv = (const float*)d_in[5];
  const float* bv = (const float*)d_in[6];
  const float* wo = (const float*)d_in[7];
  const float* bo = (const float*)d_in[8];
  const int* graph = (const int*)d_in[9];

  float* out0 = (float*)d_out;                 // (B,N,D) final output
  float* attnp = out0 + (size_t)B * N * D;     // (B,H,N,N)

  // scratch packed into attn rows [0, SROWS=10240) — exactly 10M floats:
  // O16 OVERLAYS A16 (A16 dead after gemm_qkv; pass1 writes O16 there).
  const size_t M1 = (size_t)1024 * 1024;
  unsigned short* qkv16 = (unsigned short*)attnp;              // [0, 6M)
  unsigned short* A16 = (unsigned short*)(attnp + 6 * M1);     // [6M, 8M)
  unsigned short* O16 = A16;                                   // overlay
  unsigned short* BTh = (unsigned short*)(attnp + 8 * M1);     // [8M, 9.5M)
  unsigned short* WoTh = (unsigned short*)(attnp + 9 * M1 + 524288); // [9.5M, 10M)

  // ws: pbuf/basebuf/vsumb; biasq+vpart OVERLAY pbuf (dead before pbuf use)
  float* pbuf = (float*)d_ws;                        // 2M floats
  float* basebuf = pbuf + (size_t)B * H * N * W;     // 65536
  float* vsumb = basebuf + (size_t)B * H * N;        // 4096
  float* biasq = pbuf;                               // 3072   (pre-pass1 only)
  float* vpart = pbuf + 4096;                        // 32768  (pre-pass1 only)

  prep_all<<<3084, 256, 0, stream>>>(hidden, wq, wk, wv, wo, bq, bk, bv,
                                     A16, BTh, WoTh, biasq);

  gemm_qkv<<<dim3(12, 32), 256, 0, stream>>>(A16, BTh, biasq, qkv16, vpart,
                                             1024, 3072);

  vsum_comb<<<16, 256, 0, stream>>>(vpart, biasq, vsumb);

  attn_pass1<<<B * 4 * N, 256, 0, stream>>>(qkv16, vsumb, graph, pbuf, basebuf,
                                            O16, attnp);

  gemm_o<<<dim3(8, 32), 256, 0, stream>>>(O16, WoTh, bo, out0, 1024, 1024);

  attn_fill_rem<<<SROWS / 2, 256, 0, stream>>>(pbuf, basebuf, graph, attnp);
}

// Round 17
// 146.197 us; speedup vs baseline: 1.4465x; 1.0179x over previous
//
#include <hip/hip_runtime.h>
#include <hip/hip_bf16.h>

constexpr int B = 4;
constexpr int N = 1024;
constexpr int D = 1024;
constexpr int H = 16;
constexpr int DEPTH = 64;
constexpr int W = 32;
constexpr int LDQKV = 3072;   // fused q|k|v row stride (f16 elements)
constexpr int SROWS = 8704;   // attn rows [0,SROWS) hold pass1-LIVE scratch
                              // (qkv16 6M | O16 2M | WoTh 0.5M = 8.5M floats;
                              //  BTh rows [8704,10240) are dead during pass1
                              //  and get fuse-written). Per-wave uniform: one
                              //  row per wave, so any bid threshold is fine.

typedef _Float16 f16x8 __attribute__((ext_vector_type(8)));
typedef float f32x4 __attribute__((ext_vector_type(4)));
typedef unsigned short us8 __attribute__((ext_vector_type(8)));
typedef unsigned short us4 __attribute__((ext_vector_type(4)));

__device__ __forceinline__ float h2f(unsigned short u) {
  return (float)__builtin_bit_cast(_Float16, u);
}

// ---------------------------------------------------------------------------
// async global->LDS, 16B per lane (wave-uniform LDS base, HW adds lane*16)
// ---------------------------------------------------------------------------
__device__ __forceinline__ void load_lds16(const void* g, void* l) {
  unsigned int lo = (unsigned int)(unsigned long long)l;
  __builtin_amdgcn_global_load_lds(
      (const __attribute__((address_space(1))) unsigned int*)g,
      (__attribute__((address_space(3))) unsigned int*)lo, 16, 0, 0);
}

// ---------------------------------------------------------------------------
// attn-row fill helper: base everywhere, p at graph positions, NT store.
// Barriers between mixed f32x4/float LDS accesses are REQUIRED (TBAA).
// Caller guarantees block-uniform path (barriers safe).
// ---------------------------------------------------------------------------
__device__ __forceinline__ void fill_row(float* rowf, const float* pbuf,
                                         const float* basebuf,
                                         const int* graph, float* attn,
                                         int row, int t) {
  const int n = row & (N - 1);
  const float base = basebuf[row];
  f32x4* rw = (f32x4*)rowf;
  rw[t] = (f32x4){base, base, base, base};
  __syncthreads();
  if (t < W) rowf[graph[n * W + t]] = pbuf[(size_t)row * W + t];
  __syncthreads();
  __builtin_nontemporal_store(rw[t], (f32x4*)(attn + (size_t)row * N) + t);
}

// ---------------------------------------------------------------------------
// Fused prep: grid sections
//   [0, 2048)       cvt_half: hidden fp32 -> A16 fp16
//   [2048, 3072)    txp_cvt:  wq/wk/wv/wo -> transposed fp16 (hi only)
//   [3072, 3084)    bias_concat
// ---------------------------------------------------------------------------
__global__ __launch_bounds__(256) void prep_all(
    const float* __restrict__ hidden, const float* __restrict__ wq,
    const float* __restrict__ wk, const float* __restrict__ wv,
    const float* __restrict__ wo, const float* __restrict__ bq,
    const float* __restrict__ bk, const float* __restrict__ bv,
    unsigned short* __restrict__ A16, unsigned short* __restrict__ BTh,
    unsigned short* __restrict__ WoTh, float* __restrict__ biasq) {
  __shared__ float sf[64][65];
  const int t = threadIdx.x;
  int blk = blockIdx.x;

  if (blk < 2048) {  // ---- cvt_half section ----
    const size_t i = ((size_t)blk * 256 + t) * 8;
    float4 a = *(const float4*)(hidden + i);
    float4 b = *(const float4*)(hidden + i + 4);
    float xs[8] = {a.x, a.y, a.z, a.w, b.x, b.y, b.z, b.w};
    us8 hv;
#pragma unroll
    for (int j = 0; j < 8; j++)
      hv[j] = __builtin_bit_cast(unsigned short, (_Float16)xs[j]);
    *(us8*)(A16 + i) = hv;
    return;
  }
  blk -= 2048;
  if (blk < 1024) {  // ---- txp_cvt sections (4 weights x 256 blocks) ----
    const int which = blk >> 8;       // 0=wq 1=wk 2=wv 3=wo
    const int sub = blk & 255;
    const float* w = which == 0 ? wq : which == 1 ? wk : which == 2 ? wv : wo;
    unsigned short* oh = which < 3 ? BTh : WoTh;
    const int rowOff = which < 3 ? which * 1024 : 0;

    const int tn = (sub & 15) * 64;   // src col block
    const int tk = (sub >> 4) * 64;   // src row block
#pragma unroll
    for (int i = 0; i < 4; i++) {
      int f = i * 256 + t;
      int r = f >> 4, c4 = (f & 15) * 4;
      float4 v = *(const float4*)(w + (size_t)(tk + r) * 1024 + tn + c4);
      sf[r][c4 + 0] = v.x; sf[r][c4 + 1] = v.y;
      sf[r][c4 + 2] = v.z; sf[r][c4 + 3] = v.w;
    }
    __syncthreads();
    const int n = t >> 2;             // out row (src col)
    const int kc = (t & 3) * 16;      // k chunk
    us8 hv[2];
#pragma unroll
    for (int half = 0; half < 2; half++) {
#pragma unroll
      for (int j = 0; j < 8; j++) {
        float x = sf[kc + half * 8 + j][n];
        hv[half][j] = __builtin_bit_cast(unsigned short, (_Float16)x);
      }
    }
    size_t dst = (size_t)(rowOff + tn + n) * 1024 + tk + kc;
    *(us8*)(oh + dst) = hv[0];
    *(us8*)(oh + dst + 8) = hv[1];
    return;
  }
  blk -= 1024;  // ---- bias_concat section (12 blocks) ----
  int i = blk * 256 + t;
  biasq[i] = i < 1024 ? bq[i] : (i < 2048 ? bk[i - 1024] : bv[i - 2048]);
}

// ---------------------------------------------------------------------------
// QKV GEMM: 128x256 tile, wave = 64x128 (acc 4x8). BK=32, 4 waves,
// 2-phase dbuf (48 KB LDS), f16 out. Granule swizzle k'=k^((r>>1)&3) on
// global source + ds_read. T1 XCD swizzle; T5 setprio.
// V-column blocks (bn >= 2048) also emit per-tile column-sum partials.
// ---------------------------------------------------------------------------
__global__ __launch_bounds__(256, 2) void gemm_qkv(
    const unsigned short* __restrict__ A16, const unsigned short* __restrict__ BTh,
    const float* __restrict__ bias, unsigned short* __restrict__ Cout,
    float* __restrict__ vpart, int K, int Nn) {
  __shared__ __align__(16) unsigned short sA[2 * 128 * 32];
  __shared__ __align__(16) unsigned short sB[2 * 256 * 32];
  __shared__ float vred[2][2][8][16];  // [wr][wc][n][fr], 2 KB

  const int tid = threadIdx.x;
  const int lane = tid & 63;
  const int wave = tid >> 6;
  const int wr = wave >> 1, wc = wave & 1;

  const int gx = gridDim.x;
  const int nwg = gx * gridDim.y;
  int bid = blockIdx.y * gx + blockIdx.x;
  bid = (bid & 7) * (nwg >> 3) + (bid >> 3);
  const int bm = (bid / gx) * 128;
  const int bn = (bid % gx) * 256;

  size_t aoff[2];
  int ldsA[2];
#pragma unroll
  for (int c = 0; c < 2; c++) {
    const int chunk = wave + 4 * c;
    const int e = chunk * 512 + lane * 8;
    const int r = e >> 5;
    const int kpos = (e >> 3) & 3;
    const int ksrc = kpos ^ ((r >> 1) & 3);
    aoff[c] = (size_t)(bm + r) * K + ksrc * 8;
    ldsA[c] = chunk * 512;
  }
  size_t boff[4];
  int ldsB[4];
#pragma unroll
  for (int c = 0; c < 4; c++) {
    const int chunk = wave + 4 * c;
    const int e = chunk * 512 + lane * 8;
    const int r = e >> 5;                   // 0..255
    const int kpos = (e >> 3) & 3;
    const int ksrc = kpos ^ ((r >> 1) & 3);
    boff[c] = (size_t)(bn + r) * K + ksrc * 8;
    ldsB[c] = chunk * 512;
  }

  const int fr = lane & 15;
  const int fkg = lane >> 4;

  int aroff[4], broff[8];
#pragma unroll
  for (int m = 0; m < 4; m++) {
    const int ra = wr * 64 + m * 16 + fr;
    aroff[m] = ra * 32 + ((fkg ^ ((ra >> 1) & 3)) << 3);
  }
#pragma unroll
  for (int n = 0; n < 8; n++) {
    const int rb = wc * 128 + n * 16 + fr;
    broff[n] = rb * 32 + ((fkg ^ ((rb >> 1) & 3)) << 3);
  }

  f32x4 acc[4][8] = {};

  const int NT = K >> 5;
#pragma unroll
  for (int c = 0; c < 2; c++) load_lds16(A16 + aoff[c], sA + ldsA[c]);
#pragma unroll
  for (int c = 0; c < 4; c++) load_lds16(BTh + boff[c], sB + ldsB[c]);
  __syncthreads();

  int cur = 0;
  for (int t = 0; t < NT; t++) {
    const int boA = cur * (128 * 32);
    const int boB = cur * (256 * 32);
    const int nxA = (cur ^ 1) * (128 * 32);
    const int nxB = (cur ^ 1) * (256 * 32);
    if (t + 1 < NT) {
      const int k0 = (t + 1) << 5;
#pragma unroll
      for (int c = 0; c < 2; c++) load_lds16(A16 + aoff[c] + k0, sA + nxA + ldsA[c]);
#pragma unroll
      for (int c = 0; c < 4; c++) load_lds16(BTh + boff[c] + k0, sB + nxB + ldsB[c]);
    }
    f16x8 a[4], bh[8];
#pragma unroll
    for (int m = 0; m < 4; m++) a[m] = *(const f16x8*)(sA + boA + aroff[m]);
#pragma unroll
    for (int n = 0; n < 8; n++) bh[n] = *(const f16x8*)(sB + boB + broff[n]);
    __builtin_amdgcn_s_setprio(1);
#pragma unroll
    for (int m = 0; m < 4; m++)
#pragma unroll
      for (int n = 0; n < 8; n++)
        acc[m][n] = __builtin_amdgcn_mfma_f32_16x16x32_f16(a[m], bh[n], acc[m][n], 0, 0, 0);
    __builtin_amdgcn_s_setprio(0);
    __syncthreads();
    cur ^= 1;
  }

  // epilogue: C/D layout col=lane&15, row=(lane>>4)*4+j; f16 out
#pragma unroll
  for (int m = 0; m < 4; m++) {
    const int row = bm + wr * 64 + m * 16 + fkg * 4;
#pragma unroll
    for (int n = 0; n < 8; n++) {
      const int col = bn + wc * 128 + n * 16 + fr;
      const float bsv = bias[col];
#pragma unroll
      for (int j = 0; j < 4; j++) {
        const float v = acc[m][n][j] + bsv;
        Cout[(size_t)(row + j) * Nn + col] =
            __builtin_bit_cast(unsigned short, (_Float16)v);
      }
    }
  }

  // V column-sum partials (block-uniform branch; barrier inside is safe)
  if (bn >= 2048) {
    float csum[8];
#pragma unroll
    for (int n = 0; n < 8; n++) {
      float s = 0.f;
#pragma unroll
      for (int m = 0; m < 4; m++)
#pragma unroll
        for (int j = 0; j < 4; j++) s += acc[m][n][j];
      s += __shfl_xor(s, 16);
      s += __shfl_xor(s, 32);
      csum[n] = s;
    }
    if (fkg == 0) {
#pragma unroll
      for (int n = 0; n < 8; n++) vred[wr][wc][n][fr] = csum[n];
    }
    __syncthreads();
    if (wr == 0 && fkg == 0) {
#pragma unroll
      for (int n = 0; n < 8; n++) {
        const int d = bn - 2048 + wc * 128 + n * 16 + fr;
        vpart[(size_t)(bm >> 7) * 1024 + d] = csum[n] + vred[1][wc][n][fr];
      }
    }
  }
}

// ---------------------------------------------------------------------------
// Vsum combine: vsum[b,d] = sum_{c=0..7} vpart[b*8+c][d] + 1024*bv[d]
// ---------------------------------------------------------------------------
__global__ __launch_bounds__(256) void vsum_comb(const float* __restrict__ vpart,
                                                 const float* __restrict__ biasq,
                                                 float* __restrict__ vsum) {
  const int i = blockIdx.x * 256 + threadIdx.x;  // b*1024 + d
  const int b = i >> 10, d = i & 1023;
  float s = 1024.0f * biasq[2048 + d];
#pragma unroll
  for (int c = 0; c < 8; c++) s += vpart[(size_t)(b * 8 + c) * 1024 + d];
  vsum[i] = s;
}

// ---------------------------------------------------------------------------
// pass1 (FUSED attn-row write): 4 heads per block, one wave per head.
// Gather-dot 32 keys, closed-form softmax, fp16 O plane; each wave stages
// its 4 KB attn row in LDS and NT-stores it — rows >= SROWS only (per-wave
// uniform). rowbuf fill + barriers run UNCONDITIONALLY (SROWS boundary is
// wave- but not block-uniform). Barriers REQUIRED between mixed f32x4/float
// LDS accesses (TBAA — round-14 failure).
// ---------------------------------------------------------------------------
__global__ __launch_bounds__(256) void attn_pass1(
    const unsigned short* __restrict__ qkv16, const float* __restrict__ vsum,
    const int* __restrict__ graph, float* __restrict__ pbuf,
    float* __restrict__ basebuf, unsigned short* __restrict__ O16,
    float* __restrict__ attn) {
  const int blk = blockIdx.x;         // b*4096 + hg*1024 + n
  const int n = blk & (N - 1);
  const int hg = (blk >> 10) & 3;
  const int b = blk >> 12;
  const int wave = threadIdx.x >> 6;
  const int lane = threadIdx.x & 63;
  const int h = hg * 4 + wave;
  const int bid = (b * H + h) * N + n;  // attn row id

  __shared__ float q_sh[4][DEPTH];
  __shared__ int g_sh[W];
  __shared__ float p_sh[4][W];
  __shared__ float rowbuf[4][N];      // 16 KB: per-wave attn row staging

  const unsigned short* qrow = qkv16 + (size_t)(b * N + n) * LDQKV + h * DEPTH;
  q_sh[wave][lane] = h2f(qrow[lane]);
  if (threadIdx.x < W) g_sh[threadIdx.x] = graph[n * W + threadIdx.x];
  __syncthreads();

  const int w = lane >> 1;
  const int half = lane & 1;
  const unsigned short* krow =
      qkv16 + 1024 + (size_t)(b * N + g_sh[w]) * LDQKV + h * DEPTH + half * 32;
  float acc = 0.f;
#pragma unroll
  for (int j8 = 0; j8 < 4; j8++) {
    us8 kv = *(const us8*)(krow + j8 * 8);
    const float* qh = &q_sh[wave][half * 32 + j8 * 8];
#pragma unroll
    for (int e = 0; e < 8; e++) acc += h2f(kv[e]) * qh[e];
  }
  acc += __shfl_xor(acc, 1);
  const float dot = acc * 0.125f;

  float m = dot;
#pragma unroll
  for (int off = 2; off < 64; off <<= 1) m = fmaxf(m, __shfl_xor(m, off));
  m = fmaxf(m, 0.f);

  const float e = expf(dot - m);
  float s = e;
#pragma unroll
  for (int off = 1; off < 64; off <<= 1) s += __shfl_xor(s, off);
  s *= 0.5f;

  const float em = expf(-m);
  const float Z = (float)(N - W) * em + s;
  const float inv = 1.f / Z;
  const float base = em * inv;   // wave-uniform
  const float pw = e * inv;

  if (half == 0) p_sh[wave][w] = pw;
  __syncthreads();

  const bool fused = (bid >= SROWS);  // wave-uniform
  if (!fused) {
    if (half == 0) pbuf[(size_t)bid * W + w] = pw;
    if (lane == 0) basebuf[bid] = base;
  }

  const unsigned short* vbase = qkv16 + 2048;
  const int col = h * DEPTH + lane;
  float ov = base * vsum[b * D + col];
#pragma unroll 4
  for (int ww = 0; ww < W; ww++) {
    ov += (p_sh[wave][ww] - base) *
          h2f(vbase[(size_t)(b * N + g_sh[ww]) * LDQKV + col]);
  }
  _Float16 hh = (_Float16)ov;
  O16[(size_t)(b * N + n) * D + col] = __builtin_bit_cast(unsigned short, hh);

  // attn-row staging: fill + barriers UNCONDITIONAL; scatter/store wave-uniform
  f32x4* rw = (f32x4*)rowbuf[wave];
  f32x4 b4v = {base, base, base, base};
#pragma unroll
  for (int i = 0; i < 4; i++) rw[lane + 64 * i] = b4v;
  __syncthreads();  // order fill before scatter (mixed-type LDS, TBAA)
  if (fused && half == 0) rowbuf[wave][g_sh[w]] = pw;
  __syncthreads();  // order scatter before vector read
  if (fused) {
    f32x4* dst = (f32x4*)(attn + (size_t)bid * N);
#pragma unroll
    for (int i = 0; i < 4; i++)
      __builtin_nontemporal_store(rw[lane + 64 * i], dst + lane + 64 * i);
  }
}

// ---------------------------------------------------------------------------
// MERGED: O-projection GEMM (256 blocks) + fill of attn rows [0,6144)
// (qkv16 region — dead after pass1; DISJOINT from gemm_o's inputs O16/WoTh
// in rows [6144,8704)). Fill blocks co-schedule with gemm_o and hide their
// HBM writes under its compute. fill reuses sA as its row buffer.
// ---------------------------------------------------------------------------
__global__ __launch_bounds__(256, 4) void gemm_o_fill(
    const unsigned short* __restrict__ A16, const unsigned short* __restrict__ BTh,
    const float* __restrict__ bias, float* __restrict__ Cout,
    const float* __restrict__ pbuf, const float* __restrict__ basebuf,
    const int* __restrict__ graph, float* __restrict__ attn, int K, int Nn) {
  __shared__ __align__(16) unsigned short sA[2 * 128 * 32];
  __shared__ __align__(16) unsigned short sB[2 * 128 * 32];

  const int blk = blockIdx.x;
  if (blk >= 256) {  // ---- fill section: rows [0, 6144) ----
    fill_row((float*)sA, pbuf, basebuf, graph, attn, blk - 256, threadIdx.x);
    return;
  }

  // ---- gemm_o section (proven 128x128, fp32 out, 2-phase dbuf) ----
  const int tid = threadIdx.x;
  const int lane = tid & 63;
  const int wave = tid >> 6;
  const int wr = wave >> 1, wc = wave & 1;

  int bid = blk;                       // nwg = 256, gx = 8 (8x32 tiles)
  bid = (bid & 7) * 32 + (bid >> 3);   // T1 XCD swizzle
  const int bm = (bid >> 3) * 128;
  const int bn = (bid & 7) * 128;

  size_t aoff[2], boff[2];
  int ldsoff[2];
#pragma unroll
  for (int c = 0; c < 2; c++) {
    const int chunk = wave + 4 * c;
    const int e = chunk * 512 + lane * 8;
    const int r = e >> 5;
    const int kpos = (e >> 3) & 3;
    const int ksrc = kpos ^ ((r >> 1) & 3);
    aoff[c] = (size_t)(bm + r) * K + ksrc * 8;
    boff[c] = (size_t)(bn + r) * K + ksrc * 8;
    ldsoff[c] = chunk * 512;
  }

  const int fr = lane & 15;
  const int fkg = lane >> 4;

  int aroff[4], broff[4];
#pragma unroll
  for (int m = 0; m < 4; m++) {
    const int ra = wr * 64 + m * 16 + fr;
    aroff[m] = ra * 32 + ((fkg ^ ((ra >> 1) & 3)) << 3);
    const int rb = wc * 64 + m * 16 + fr;
    broff[m] = rb * 32 + ((fkg ^ ((rb >> 1) & 3)) << 3);
  }

  f32x4 acc[4][4] = {};

  const int NT = K >> 5;
#pragma unroll
  for (int c = 0; c < 2; c++) {
    load_lds16(A16 + aoff[c], sA + ldsoff[c]);
    load_lds16(BTh + boff[c], sB + ldsoff[c]);
  }
  __syncthreads();

  int cur = 0;
  for (int t = 0; t < NT; t++) {
    const int bo_ = cur * (128 * 32);
    const int nx_ = (cur ^ 1) * (128 * 32);
    if (t + 1 < NT) {
      const int k0 = (t + 1) << 5;
#pragma unroll
      for (int c = 0; c < 2; c++) {
        load_lds16(A16 + aoff[c] + k0, sA + nx_ + ldsoff[c]);
        load_lds16(BTh + boff[c] + k0, sB + nx_ + ldsoff[c]);
      }
    }
    f16x8 a[4], bh[4];
#pragma unroll
    for (int m = 0; m < 4; m++) a[m] = *(const f16x8*)(sA + bo_ + aroff[m]);
#pragma unroll
    for (int n = 0; n < 4; n++) bh[n] = *(const f16x8*)(sB + bo_ + broff[n]);
    __builtin_amdgcn_s_setprio(1);
#pragma unroll
    for (int m = 0; m < 4; m++)
#pragma unroll
      for (int n = 0; n < 4; n++)
        acc[m][n] = __builtin_amdgcn_mfma_f32_16x16x32_f16(a[m], bh[n], acc[m][n], 0, 0, 0);
    __builtin_amdgcn_s_setprio(0);
    __syncthreads();
    cur ^= 1;
  }

#pragma unroll
  for (int m = 0; m < 4; m++) {
    const int row = bm + wr * 64 + m * 16 + fkg * 4;
#pragma unroll
    for (int n = 0; n < 4; n++) {
      const int col = bn + wc * 64 + n * 16 + fr;
      const float bsv = bias[col];
#pragma unroll
      for (int j = 0; j < 4; j++)
        Cout[(size_t)(row + j) * Nn + col] = acc[m][n][j] + bsv;
    }
  }
}

// ---------------------------------------------------------------------------
// Last fill: rows [6144, 8704) — O16/WoTh regions, consumed by gemm_o_fill.
// ---------------------------------------------------------------------------
__global__ __launch_bounds__(256) void attn_fill_last(
    const float* __restrict__ pbuf, const float* __restrict__ basebuf,
    const int* __restrict__ graph, float* __restrict__ attn) {
  __shared__ __align__(16) float rowf[N];
  fill_row(rowf, pbuf, basebuf, graph, attn, 6144 + blockIdx.x, threadIdx.x);
}

// ---------------------------------------------------------------------------
extern "C" void kernel_launch(void* const* d_in, const int* in_sizes, int n_in,
                              void* d_out, int out_size, void* d_ws, size_t ws_size,
                              hipStream_t stream) {
  const float* hidden = (const float*)d_in[0];
  const float* wq = (const float*)d_in[1];
  const float* bq = (const float*)d_in[2];
  const float* wk = (const float*)d_in[3];
  const float* bk = (const float*)d_in[4];
  const float* wv = (const float*)d_in[5];
  const float* bv = (const float*)d_in[6];
  const float* wo = (const float*)d_in[7];
  const float* bo = (const float*)d_in[8];
  const int* graph = (const int*)d_in[9];

  float* out0 = (float*)d_out;                 // (B,N,D) final output
  float* attnp = out0 + (size_t)B * N * D;     // (B,H,N,N)

  // scratch in attn rows:
  //   [0,   6M): qkv16   (live through pass1)
  //   [6M,  8M): A16 / O16 overlay (O16 live through gemm_o_fill)
  //   [8M, 8.5M): WoTh   (live through gemm_o_fill)
  //   [8.5M,10M): BTh    (dead after gemm_qkv -> fuse-written by pass1)
  const size_t M1 = (size_t)1024 * 1024;
  unsigned short* qkv16 = (unsigned short*)attnp;
  unsigned short* A16 = (unsigned short*)(attnp + 6 * M1);
  unsigned short* O16 = A16;                                   // overlay
  unsigned short* WoTh = (unsigned short*)(attnp + 8 * M1);
  unsigned short* BTh = (unsigned short*)(attnp + 8 * M1 + 524288);

  // ws: pbuf/basebuf/vsumb; biasq+vpart OVERLAY pbuf (dead before pbuf use)
  float* pbuf = (float*)d_ws;                        // 2M floats
  float* basebuf = pbuf + (size_t)B * H * N * W;     // 65536
  float* vsumb = basebuf + (size_t)B * H * N;        // 4096
  float* biasq = pbuf;                               // 3072   (pre-pass1 only)
  float* vpart = pbuf + 4096;                        // 32768  (pre-pass1 only)

  prep_all<<<3084, 256, 0, stream>>>(hidden, wq, wk, wv, wo, bq, bk, bv,
                                     A16, BTh, WoTh, biasq);

  gemm_qkv<<<dim3(12, 32), 256, 0, stream>>>(A16, BTh, biasq, qkv16, vpart,
                                             1024, 3072);

  vsum_comb<<<16, 256, 0, stream>>>(vpart, biasq, vsumb);

  attn_pass1<<<B * 4 * N, 256, 0, stream>>>(qkv16, vsumb, graph, pbuf, basebuf,
                                            O16, attnp);

  // merged: O-projection (256 blocks) + fill rows [0,6144) (6144 blocks)
  gemm_o_fill<<<256 + 6144, 256, 0, stream>>>(O16, WoTh, bo, out0, pbuf,
                                              basebuf, graph, attnp,
                                              1024, 1024);

  attn_fill_last<<<8704 - 6144, 256, 0, stream>>>(pbuf, basebuf, graph, attnp);
}